// Round 3
// baseline (8249.180 us; speedup 1.0000x reference)
//
#include <hip/hip_runtime.h>

#define NN 32768
#define NE 131072
#define NB 512
#define SL 1000

// ---------------- degree / normalization ----------------
__global__ void k_deg(const int* __restrict__ dst, float* __restrict__ deg, int E) {
  int e = blockIdx.x * 256 + threadIdx.x;
  if (e < E) atomicAdd(&deg[dst[e]], 1.0f);
}
__global__ void k_dis(float* d, int N) {
  int i = blockIdx.x * 256 + threadIdx.x;
  if (i < N) d[i] = rsqrtf(1.0f + d[i]);
}

// ---------------- generic dense layer ----------------
// out[n][co] = (relu)(bias + in[n][:] @ W);  if SELF: out2[n][co] = out[n][co]*dis[n]^2
// W layout [K][C_OUT]. Thread computes 4 consecutive co for one n.
// NOTE: out2 must NOT alias in (race) — only use SELF when in is a distinct buffer.
template<int C_OUT, int K, bool RELU, bool BIAS, bool SELF>
__launch_bounds__(256)
__global__ void k_fc(const float* __restrict__ in, const float* __restrict__ W,
                     const float* __restrict__ bias, const float* __restrict__ dis,
                     float* __restrict__ out, float* __restrict__ out2, int N) {
  constexpr int CO4 = C_OUT / 4;
  int gid = blockIdx.x * 256 + threadIdx.x;
  int n = gid / CO4;
  if (n >= N) return;
  int co = (gid - n * CO4) * 4;
  const float* row = in + (long)n * K;
  float ax = 0.f, ay = 0.f, az = 0.f, aw = 0.f;
  if (BIAS) {
    float4 b4 = *(const float4*)&bias[co];
    ax = b4.x; ay = b4.y; az = b4.z; aw = b4.w;
  }
#pragma unroll 4
  for (int ci = 0; ci < K; ++ci) {
    float a = row[ci];
    float4 w = *(const float4*)&W[(long)ci * C_OUT + co];
    ax += a * w.x; ay += a * w.y; az += a * w.z; aw += a * w.w;
  }
  if (RELU) {
    ax = fmaxf(ax, 0.f); ay = fmaxf(ay, 0.f); az = fmaxf(az, 0.f); aw = fmaxf(aw, 0.f);
  }
  float4 o; o.x = ax; o.y = ay; o.z = az; o.w = aw;
  *(float4*)&out[(long)n * C_OUT + co] = o;
  if (SELF) {
    float s = dis[n]; s = s * s;
    float4 o2; o2.x = ax * s; o2.y = ay * s; o2.z = az * s; o2.w = aw * s;
    *(float4*)&out2[(long)n * C_OUT + co] = o2;
  }
}

// ---------------- GCN self-loop term: agg = xw * dis[n]^2 ----------------
template<int C>
__global__ void k_selfscale(const float* __restrict__ xw, const float* __restrict__ dis,
                            float* __restrict__ agg, int N) {
  constexpr int C4 = C / 4;
  int gid = blockIdx.x * 256 + threadIdx.x;
  int n = gid / C4;
  if (n >= N) return;
  int c = (gid - n * C4) * 4;
  float s = dis[n]; s = s * s;
  float4 v = *(const float4*)&xw[(long)n * C + c];
  v.x *= s; v.y *= s; v.z *= s; v.w *= s;
  *(float4*)&agg[(long)n * C + c] = v;
}

// ---------------- edge scatter: agg[dst] += xw[src] * dis[src]*dis[dst] ----------------
template<int C>
__global__ void k_scatter(const float* __restrict__ xw, const float* __restrict__ dis,
                          const int* __restrict__ src, const int* __restrict__ dst,
                          float* __restrict__ agg, int E) {
  constexpr int C4 = C / 4;
  int gid = blockIdx.x * 256 + threadIdx.x;
  int e = gid / C4;
  if (e >= E) return;
  int c = (gid - e * C4) * 4;
  int s = src[e], d = dst[e];
  float coef = dis[s] * dis[d];
  float4 v = *(const float4*)&xw[(long)s * C + c];
  float* p = &agg[(long)d * C + c];
  atomicAdd(p + 0, v.x * coef);
  atomicAdd(p + 1, v.y * coef);
  atomicAdd(p + 2, v.z * coef);
  atomicAdd(p + 3, v.w * coef);
}

// ---------------- batchnorm: stats (sum, sumsq per channel) ----------------
template<int C>
__global__ void k_bnstats(const float* __restrict__ h, float* __restrict__ stats, int N) {
  constexpr int RPB = 256 / C;
  int c = threadIdx.x % C;
  int r = threadIdx.x / C;
  float s = 0.f, ss = 0.f;
  for (int n = blockIdx.x * RPB + r; n < N; n += gridDim.x * RPB) {
    float v = h[(long)n * C + c];
    s += v; ss += v * v;
  }
  __shared__ float ls[256], lss[256];
  ls[threadIdx.x] = s; lss[threadIdx.x] = ss;
  __syncthreads();
  if (threadIdx.x < C) {
    float st = 0.f, sst = 0.f;
#pragma unroll
    for (int r2 = 0; r2 < RPB; ++r2) { st += ls[c + r2 * C]; sst += lss[c + r2 * C]; }
    atomicAdd(&stats[c], st);
    atomicAdd(&stats[C + c], sst);
  }
}

// stats -> (scale, shift); GCN bias b dropped upstream: _bn(x+b)==_bn(x)
template<int C>
__global__ void k_bnfinal(float* stats, const float* __restrict__ g,
                          const float* __restrict__ bt, int N) {
  int c = threadIdx.x;
  float m = stats[c] / (float)N;
  float v = stats[C + c] / (float)N - m * m;
  float sc = g[c] * rsqrtf(v + 1e-5f);
  stats[c] = sc;
  stats[C + c] = bt[c] - m * sc;
}

template<int C>
__global__ void k_bnrelu(float* __restrict__ h, const float* __restrict__ stats, int N) {
  constexpr int C4 = C / 4;
  int gid = blockIdx.x * 256 + threadIdx.x;
  int n = gid / C4;
  if (n >= N) return;
  int c = (gid - n * C4) * 4;
  float4 v = *(float4*)&h[(long)n * C + c];
  float4 sc = *(const float4*)&stats[c];
  float4 sh = *(const float4*)&stats[C + c];
  v.x = fmaxf(v.x * sc.x + sh.x, 0.f);
  v.y = fmaxf(v.y * sc.y + sh.y, 0.f);
  v.z = fmaxf(v.z * sc.z + sh.z, 0.f);
  v.w = fmaxf(v.w * sc.w + sh.w, 0.f);
  *(float4*)&h[(long)n * C + c] = v;
}

// ---------------- graph mean-pool into cbuf[:, 0:128] ----------------
__global__ void k_pool(const float* __restrict__ h, const int* __restrict__ batch,
                       float* __restrict__ cbuf, float* __restrict__ cnt, int N) {
  int gid = blockIdx.x * 256 + threadIdx.x;
  int n = gid >> 5;
  if (n >= N) return;
  int c = (gid & 31) * 4;
  int b = batch[n];
  float4 v = *(const float4*)&h[(long)n * 128 + c];
  float* p = &cbuf[b * 224 + c];
  atomicAdd(p + 0, v.x); atomicAdd(p + 1, v.y);
  atomicAdd(p + 2, v.z); atomicAdd(p + 3, v.w);
  if ((gid & 31) == 0) atomicAdd(&cnt[b], 1.0f);
}
__global__ void k_pooldiv(float* cbuf, const float* __restrict__ cnt) {
  int gid = blockIdx.x * 256 + threadIdx.x;  // 512*128
  int b = gid >> 7, c = gid & 127;
  cbuf[b * 224 + c] *= 1.0f / fmaxf(cnt[b], 1.0f);
}

// ---------------- fused protein encoder ----------------
// Tile of 48 conv3 outputs per block. Embedding TABLE (26x128 = 13KB) cached in
// LDS; per-position input vectors are gathered on the fly via token ids (token 0
// row is all-zero => out-of-range positions use tok=0).
// Halo mapping for tile base t0 = tile*48:
//   input position p = t0 - 6 + j           (tokens j in [0,67))
//   s_c1[j]  <-> conv1 output l1 = t0-5+j,  j in [0,60)
//   s_c2[j]  <-> conv2 output l2 = t0-3+j,  j in [0,55)
//   conv3 output l3 = t0 + j3, j3 in [0,48), valid l3 < 997
// LDS: 13312 + 272 + 7808 + 14080 + 384 = 35856 B -> 4 blocks/CU by LDS.
__launch_bounds__(256, 4)
__global__ void conv_fused(const int* __restrict__ seq, const float* __restrict__ emb,
                           const float* __restrict__ ck1, const float* __restrict__ cb1,
                           const float* __restrict__ ck2, const float* __restrict__ cb2,
                           const float* __restrict__ ck3, const float* __restrict__ cb3,
                           float* __restrict__ outmax) {
  __shared__ float s_emb[26 * 128];
  __shared__ int s_tok[68];
  __shared__ float s_c1[61][32];   // row 60 written-zero guard region
  __shared__ float s_c2[55][64];
  __shared__ int s_max[96];

  int tid = threadIdx.x;
  int tile = blockIdx.x;
  int b = blockIdx.y;
  int t0 = tile * 48;

  if (tid < 96) s_max[tid] = 0;
  // embedding table -> LDS (832 float4)
  for (int idx = tid; idx < 26 * 32; idx += 256) {
    ((float4*)s_emb)[idx] = ((const float4*)emb)[idx];
  }
  // token ids (out-of-range -> 0; emb row 0 is the zeroed padding row)
  if (tid < 67) {
    int p = t0 - 6 + tid;
    s_tok[tid] = (p >= 0 && p < SL) ? seq[b * SL + p] : 0;
  }
  __syncthreads();

  // ---- stage 1: conv1  Cin=128 K=4 Cout=32, outputs j in [0,60)
  {
    int co = tid & 31, jg = tid >> 5;
    int tok[11];
#pragma unroll
    for (int r = 0; r < 11; ++r) tok[r] = s_tok[jg * 8 + r];
    float acc[8];
    float bv = cb1[co];
#pragma unroll
    for (int i = 0; i < 8; ++i) acc[i] = bv;
    for (int c4 = 0; c4 < 32; ++c4) {
      float a[11][4];
#pragma unroll
      for (int r = 0; r < 11; ++r) {
        float4 t4 = *(const float4*)&s_emb[tok[r] * 128 + c4 * 4];
        a[r][0] = t4.x; a[r][1] = t4.y; a[r][2] = t4.z; a[r][3] = t4.w;
      }
      const float* wp = ck1 + co * 512 + c4 * 16;  // [co][ci][k], 16 contiguous
#pragma unroll
      for (int cc = 0; cc < 4; ++cc) {
        float4 w4 = *(const float4*)(wp + cc * 4);
        float wk[4] = {w4.x, w4.y, w4.z, w4.w};
#pragma unroll
        for (int k = 0; k < 4; ++k) {
          float wv = wk[k];
#pragma unroll
          for (int i = 0; i < 8; ++i) acc[i] += a[i + k][cc] * wv;
        }
      }
    }
#pragma unroll
    for (int i = 0; i < 8; ++i) {
      int j = jg * 8 + i;
      if (j < 60) {
        int l1 = t0 - 5 + j;
        s_c1[j][co] = (l1 >= 0 && l1 < 999) ? fmaxf(acc[i], 0.f) : 0.f;
      }
    }
  }
  __syncthreads();

  // ---- stage 2: conv2  Cin=32 K=6 Cout=64, outputs j in [0,55)
  {
    int cp = tid & 31, jg = tid >> 5;
    int co0 = cp * 2;
    float acc[7][2];
    {
      float b0 = cb2[co0], b1 = cb2[co0 + 1];
#pragma unroll
      for (int i = 0; i < 7; ++i) { acc[i][0] = b0; acc[i][1] = b1; }
    }
    for (int c4 = 0; c4 < 8; ++c4) {
      float a[12][4];
#pragma unroll
      for (int r = 0; r < 12; ++r) {
        float4 t4 = *(const float4*)&s_c1[jg * 7 + r][c4 * 4];
        a[r][0] = t4.x; a[r][1] = t4.y; a[r][2] = t4.z; a[r][3] = t4.w;
      }
      const float* p0 = ck2 + co0 * 192 + c4 * 24;  // [co][ci][k]
#pragma unroll
      for (int cc = 0; cc < 4; ++cc) {
        float w0[6], w1[6];
#pragma unroll
        for (int q = 0; q < 3; ++q) {
          float2 u0 = *(const float2*)(p0 + cc * 6 + q * 2);
          float2 u1 = *(const float2*)(p0 + 192 + cc * 6 + q * 2);
          w0[q * 2] = u0.x; w0[q * 2 + 1] = u0.y;
          w1[q * 2] = u1.x; w1[q * 2 + 1] = u1.y;
        }
#pragma unroll
        for (int k = 0; k < 6; ++k) {
#pragma unroll
          for (int i = 0; i < 7; ++i) {
            acc[i][0] += a[i + k][cc] * w0[k];
            acc[i][1] += a[i + k][cc] * w1[k];
          }
        }
      }
    }
#pragma unroll
    for (int i = 0; i < 7; ++i) {
      int j = jg * 7 + i;
      if (j < 55) {
        int l2 = t0 - 3 + j;
        bool ok = (l2 >= 0 && l2 < 998);
        s_c2[j][co0] = ok ? fmaxf(acc[i][0], 0.f) : 0.f;
        s_c2[j][co0 + 1] = ok ? fmaxf(acc[i][1], 0.f) : 0.f;
      }
    }
  }
  __syncthreads();

  // ---- stage 3: conv3  Cin=64 K=8 Cout=96, outputs j in [0,48), + relu-max
  {
    int ct = tid & 31, jg = tid >> 5;
    int co0 = ct * 3;
    float acc[6][3];
    {
      float b0 = cb3[co0], b1 = cb3[co0 + 1], b2 = cb3[co0 + 2];
#pragma unroll
      for (int i = 0; i < 6; ++i) { acc[i][0] = b0; acc[i][1] = b1; acc[i][2] = b2; }
    }
    for (int c4 = 0; c4 < 16; ++c4) {
      float a[13][4];
#pragma unroll
      for (int r = 0; r < 13; ++r) {
        float4 t4 = *(const float4*)&s_c2[jg * 6 + r][c4 * 4];
        a[r][0] = t4.x; a[r][1] = t4.y; a[r][2] = t4.z; a[r][3] = t4.w;
      }
#pragma unroll
      for (int t = 0; t < 3; ++t) {
        const float* wp = ck3 + (co0 + t) * 512 + c4 * 32;  // [4cc][8k] chunk
#pragma unroll
        for (int cc = 0; cc < 4; ++cc) {
          float4 wa = *(const float4*)(wp + cc * 8);
          float4 wb = *(const float4*)(wp + cc * 8 + 4);
          float wk[8] = {wa.x, wa.y, wa.z, wa.w, wb.x, wb.y, wb.z, wb.w};
#pragma unroll
          for (int k = 0; k < 8; ++k) {
            float wv = wk[k];
#pragma unroll
            for (int i = 0; i < 6; ++i) acc[i][t] += a[i + k][cc] * wv;
          }
        }
      }
    }
    float m0 = 0.f, m1 = 0.f, m2 = 0.f;  // relu folded into max(0,.)
#pragma unroll
    for (int i = 0; i < 6; ++i) {
      int l3 = t0 + jg * 6 + i;
      if (l3 < 997) {
        m0 = fmaxf(m0, acc[i][0]);
        m1 = fmaxf(m1, acc[i][1]);
        m2 = fmaxf(m2, acc[i][2]);
      }
    }
    atomicMax(&s_max[co0], __float_as_int(m0));
    atomicMax(&s_max[co0 + 1], __float_as_int(m1));
    atomicMax(&s_max[co0 + 2], __float_as_int(m2));
  }
  __syncthreads();
  if (tid < 96) atomicMax((int*)&outmax[b * 224 + 128 + tid], s_max[tid]);
}

// ---------------- final 256 -> 1 ----------------
__global__ void k_fc3(const float* __restrict__ in, const float* __restrict__ w,
                      const float* __restrict__ bias, float* __restrict__ out) {
  int b = blockIdx.x * 256 + threadIdx.x;
  if (b >= NB) return;
  float acc = bias[0];
#pragma unroll 4
  for (int k = 0; k < 256; ++k) acc += in[b * 256 + k] * w[k];
  out[b] = acc;
}

extern "C" void kernel_launch(void* const* d_in, const int* in_sizes, int n_in,
                              void* d_out, int out_size, void* d_ws, size_t ws_size,
                              hipStream_t stream) {
  (void)in_sizes; (void)n_in; (void)out_size; (void)ws_size;
  const float* x = (const float*)d_in[0];
  const int* ei = (const int*)d_in[1];
  const int* batch = (const int*)d_in[2];
  const int* seq = (const int*)d_in[3];
  const float* W1 = (const float*)d_in[4];
  // b1/b2/b3 (d_in[5,9,13]) dropped: constant channel bias cancels in BatchNorm
  const float* g1 = (const float*)d_in[6];
  const float* bt1 = (const float*)d_in[7];
  const float* W2 = (const float*)d_in[8];
  const float* g2 = (const float*)d_in[10];
  const float* bt2 = (const float*)d_in[11];
  const float* W3 = (const float*)d_in[12];
  const float* g3 = (const float*)d_in[14];
  const float* bt3 = (const float*)d_in[15];
  const float* emb = (const float*)d_in[16];
  const float* ck1 = (const float*)d_in[17];
  const float* cb1 = (const float*)d_in[18];
  const float* ck2 = (const float*)d_in[19];
  const float* cb2 = (const float*)d_in[20];
  const float* ck3 = (const float*)d_in[21];
  const float* cb3 = (const float*)d_in[22];
  const float* fw1 = (const float*)d_in[23];
  const float* fb1 = (const float*)d_in[24];
  const float* fw2 = (const float*)d_in[25];
  const float* fb2 = (const float*)d_in[26];
  const float* fw3 = (const float*)d_in[27];
  const float* fb3 = (const float*)d_in[28];
  const int* src = ei;
  const int* dst = ei + NE;

  float* ws = (float*)d_ws;
  float* bufA = ws;                 // 32768*128 (16 MB): agg / h (in-place)
  float* bufB = ws + 4194304;       // 32768*128 (16 MB): xw / fc scratch
  float* dis = ws + 8388608;        // 32768
  float* stats = ws + 8421376;      // 256
  float* cbuf = ws + 8421632;       // 512*224 concat features
  float* cnt2 = ws + 8536320;       // 512
  float* out = (float*)d_out;

  hipMemsetAsync(dis, 0, NN * sizeof(float), stream);
  hipMemsetAsync(cbuf, 0, NB * 224 * sizeof(float), stream);
  hipMemsetAsync(cnt2, 0, NB * sizeof(float), stream);

  k_deg<<<NE / 256, 256, 0, stream>>>(dst, dis, NE);
  k_dis<<<NN / 256, 256, 0, stream>>>(dis, NN);

  // ---- GCN layer 1 (5 -> 64): in=x distinct, so fused self-term is safe
  k_fc<64, 5, false, false, true><<<NN * 16 / 256, 256, 0, stream>>>(x, W1, nullptr, dis, bufB, bufA, NN);
  k_scatter<64><<<NE * 16 / 256, 256, 0, stream>>>(bufB, dis, src, dst, bufA, NE);
  hipMemsetAsync(stats, 0, 128 * sizeof(float), stream);
  k_bnstats<64><<<256, 256, 0, stream>>>(bufA, stats, NN);
  k_bnfinal<64><<<1, 64, 0, stream>>>(stats, g1, bt1, NN);
  k_bnrelu<64><<<NN * 16 / 256, 256, 0, stream>>>(bufA, stats, NN);

  // ---- GCN layer 2 (64 -> 128): in=bufA, so self-term must be a separate pass
  k_fc<128, 64, false, false, false><<<NN * 32 / 256, 256, 0, stream>>>(bufA, W2, nullptr, nullptr, bufB, nullptr, NN);
  k_selfscale<128><<<NN * 32 / 256, 256, 0, stream>>>(bufB, dis, bufA, NN);
  k_scatter<128><<<NE * 32 / 256, 256, 0, stream>>>(bufB, dis, src, dst, bufA, NE);
  hipMemsetAsync(stats, 0, 256 * sizeof(float), stream);
  k_bnstats<128><<<256, 256, 0, stream>>>(bufA, stats, NN);
  k_bnfinal<128><<<1, 128, 0, stream>>>(stats, g2, bt2, NN);
  k_bnrelu<128><<<NN * 32 / 256, 256, 0, stream>>>(bufA, stats, NN);

  // ---- GCN layer 3 (128 -> 128)
  k_fc<128, 128, false, false, false><<<NN * 32 / 256, 256, 0, stream>>>(bufA, W3, nullptr, nullptr, bufB, nullptr, NN);
  k_selfscale<128><<<NN * 32 / 256, 256, 0, stream>>>(bufB, dis, bufA, NN);
  k_scatter<128><<<NE * 32 / 256, 256, 0, stream>>>(bufB, dis, src, dst, bufA, NE);
  hipMemsetAsync(stats, 0, 256 * sizeof(float), stream);
  k_bnstats<128><<<256, 256, 0, stream>>>(bufA, stats, NN);
  k_bnfinal<128><<<1, 128, 0, stream>>>(stats, g3, bt3, NN);
  k_bnrelu<128><<<NN * 32 / 256, 256, 0, stream>>>(bufA, stats, NN);

  // ---- graph mean pool -> cbuf[:, 0:128]
  k_pool<<<NN * 32 / 256, 256, 0, stream>>>(bufA, batch, cbuf, cnt2, NN);
  k_pooldiv<<<NB * 128 / 256, 256, 0, stream>>>(cbuf, cnt2);

  // ---- protein encoder -> cbuf[:, 128:224]
  conv_fused<<<dim3(21, NB), 256, 0, stream>>>(seq, emb, ck1, cb1, ck2, cb2, ck3, cb3, cbuf);

  // ---- regressor
  k_fc<512, 224, true, true, false><<<NB * 128 / 256, 256, 0, stream>>>(cbuf, fw1, fb1, nullptr, bufB, nullptr, NB);
  k_fc<256, 512, true, true, false><<<NB * 64 / 256, 256, 0, stream>>>(bufB, fw2, fb2, nullptr, bufA, nullptr, NB);
  k_fc3<<<2, 256, 0, stream>>>(bufA, fw3, fb3, out);
}

// Round 4
// 4108.994 us; speedup vs baseline: 2.0076x; 2.0076x over previous
//
#include <hip/hip_runtime.h>

#define NN 32768
#define NE 131072
#define NB 512
#define SL 1000

// ---------------- degree / normalization ----------------
__global__ void k_deg(const int* __restrict__ dst, float* __restrict__ deg, int E) {
  int e = blockIdx.x * 256 + threadIdx.x;
  if (e < E) atomicAdd(&deg[dst[e]], 1.0f);
}
__global__ void k_dis(float* d, int N) {
  int i = blockIdx.x * 256 + threadIdx.x;
  if (i < N) d[i] = rsqrtf(1.0f + d[i]);
}

// ---------------- generic dense layer ----------------
// out[n][co] = (relu)(bias + in[n][:] @ W);  if SELF: out2[n][co] = out[n][co]*dis[n]^2
// W layout [K][C_OUT]. Thread computes 4 consecutive co for one n.
// NOTE: out2 must NOT alias in (race) — only use SELF when in is a distinct buffer.
template<int C_OUT, int K, bool RELU, bool BIAS, bool SELF>
__launch_bounds__(256)
__global__ void k_fc(const float* __restrict__ in, const float* __restrict__ W,
                     const float* __restrict__ bias, const float* __restrict__ dis,
                     float* __restrict__ out, float* __restrict__ out2, int N) {
  constexpr int CO4 = C_OUT / 4;
  int gid = blockIdx.x * 256 + threadIdx.x;
  int n = gid / CO4;
  if (n >= N) return;
  int co = (gid - n * CO4) * 4;
  const float* row = in + (long)n * K;
  float ax = 0.f, ay = 0.f, az = 0.f, aw = 0.f;
  if (BIAS) {
    float4 b4 = *(const float4*)&bias[co];
    ax = b4.x; ay = b4.y; az = b4.z; aw = b4.w;
  }
#pragma unroll 4
  for (int ci = 0; ci < K; ++ci) {
    float a = row[ci];
    float4 w = *(const float4*)&W[(long)ci * C_OUT + co];
    ax += a * w.x; ay += a * w.y; az += a * w.z; aw += a * w.w;
  }
  if (RELU) {
    ax = fmaxf(ax, 0.f); ay = fmaxf(ay, 0.f); az = fmaxf(az, 0.f); aw = fmaxf(aw, 0.f);
  }
  float4 o; o.x = ax; o.y = ay; o.z = az; o.w = aw;
  *(float4*)&out[(long)n * C_OUT + co] = o;
  if (SELF) {
    float s = dis[n]; s = s * s;
    float4 o2; o2.x = ax * s; o2.y = ay * s; o2.z = az * s; o2.w = aw * s;
    *(float4*)&out2[(long)n * C_OUT + co] = o2;
  }
}

// ---------------- GCN self-loop term: agg = xw * dis[n]^2 ----------------
template<int C>
__global__ void k_selfscale(const float* __restrict__ xw, const float* __restrict__ dis,
                            float* __restrict__ agg, int N) {
  constexpr int C4 = C / 4;
  int gid = blockIdx.x * 256 + threadIdx.x;
  int n = gid / C4;
  if (n >= N) return;
  int c = (gid - n * C4) * 4;
  float s = dis[n]; s = s * s;
  float4 v = *(const float4*)&xw[(long)n * C + c];
  v.x *= s; v.y *= s; v.z *= s; v.w *= s;
  *(float4*)&agg[(long)n * C + c] = v;
}

// ---------------- edge scatter: agg[dst] += xw[src] * dis[src]*dis[dst] ----------------
template<int C>
__global__ void k_scatter(const float* __restrict__ xw, const float* __restrict__ dis,
                          const int* __restrict__ src, const int* __restrict__ dst,
                          float* __restrict__ agg, int E) {
  constexpr int C4 = C / 4;
  int gid = blockIdx.x * 256 + threadIdx.x;
  int e = gid / C4;
  if (e >= E) return;
  int c = (gid - e * C4) * 4;
  int s = src[e], d = dst[e];
  float coef = dis[s] * dis[d];
  float4 v = *(const float4*)&xw[(long)s * C + c];
  float* p = &agg[(long)d * C + c];
  atomicAdd(p + 0, v.x * coef);
  atomicAdd(p + 1, v.y * coef);
  atomicAdd(p + 2, v.z * coef);
  atomicAdd(p + 3, v.w * coef);
}

// ---------------- batchnorm: stats (sum, sumsq per channel) ----------------
template<int C>
__global__ void k_bnstats(const float* __restrict__ h, float* __restrict__ stats, int N) {
  constexpr int RPB = 256 / C;
  int c = threadIdx.x % C;
  int r = threadIdx.x / C;
  float s = 0.f, ss = 0.f;
  for (int n = blockIdx.x * RPB + r; n < N; n += gridDim.x * RPB) {
    float v = h[(long)n * C + c];
    s += v; ss += v * v;
  }
  __shared__ float ls[256], lss[256];
  ls[threadIdx.x] = s; lss[threadIdx.x] = ss;
  __syncthreads();
  if (threadIdx.x < C) {
    float st = 0.f, sst = 0.f;
#pragma unroll
    for (int r2 = 0; r2 < RPB; ++r2) { st += ls[c + r2 * C]; sst += lss[c + r2 * C]; }
    atomicAdd(&stats[c], st);
    atomicAdd(&stats[C + c], sst);
  }
}

// stats -> (scale, shift); GCN bias b dropped upstream: _bn(x+b)==_bn(x)
template<int C>
__global__ void k_bnfinal(float* stats, const float* __restrict__ g,
                          const float* __restrict__ bt, int N) {
  int c = threadIdx.x;
  float m = stats[c] / (float)N;
  float v = stats[C + c] / (float)N - m * m;
  float sc = g[c] * rsqrtf(v + 1e-5f);
  stats[c] = sc;
  stats[C + c] = bt[c] - m * sc;
}

template<int C>
__global__ void k_bnrelu(float* __restrict__ h, const float* __restrict__ stats, int N) {
  constexpr int C4 = C / 4;
  int gid = blockIdx.x * 256 + threadIdx.x;
  int n = gid / C4;
  if (n >= N) return;
  int c = (gid - n * C4) * 4;
  float4 v = *(float4*)&h[(long)n * C + c];
  float4 sc = *(const float4*)&stats[c];
  float4 sh = *(const float4*)&stats[C + c];
  v.x = fmaxf(v.x * sc.x + sh.x, 0.f);
  v.y = fmaxf(v.y * sc.y + sh.y, 0.f);
  v.z = fmaxf(v.z * sc.z + sh.z, 0.f);
  v.w = fmaxf(v.w * sc.w + sh.w, 0.f);
  *(float4*)&h[(long)n * C + c] = v;
}

// ---------------- graph mean-pool into cbuf[:, 0:128] ----------------
__global__ void k_pool(const float* __restrict__ h, const int* __restrict__ batch,
                       float* __restrict__ cbuf, float* __restrict__ cnt, int N) {
  int gid = blockIdx.x * 256 + threadIdx.x;
  int n = gid >> 5;
  if (n >= N) return;
  int c = (gid & 31) * 4;
  int b = batch[n];
  float4 v = *(const float4*)&h[(long)n * 128 + c];
  float* p = &cbuf[b * 224 + c];
  atomicAdd(p + 0, v.x); atomicAdd(p + 1, v.y);
  atomicAdd(p + 2, v.z); atomicAdd(p + 3, v.w);
  if ((gid & 31) == 0) atomicAdd(&cnt[b], 1.0f);
}
__global__ void k_pooldiv(float* cbuf, const float* __restrict__ cnt) {
  int gid = blockIdx.x * 256 + threadIdx.x;  // 512*128
  int b = gid >> 7, c = gid & 127;
  cbuf[b * 224 + c] *= 1.0f / fmaxf(cnt[b], 1.0f);
}

// ---------------- fused protein encoder ----------------
// Tile of 48 conv3 outputs per block. Embedding TABLE (26x128 = 13KB) cached in
// LDS; per-position input vectors are gathered on the fly via token ids (token 0
// row is all-zero => out-of-range positions use tok=0).
// Halo mapping for tile base t0 = tile*48:
//   input position p = t0 - 6 + j           (tokens j in [0,67))
//   s_c1[j]  <-> conv1 output l1 = t0-5+j,  j in [0,60)
//   s_c2[j]  <-> conv2 output l2 = t0-3+j,  j in [0,55)
//   conv3 output l3 = t0 + j3, j3 in [0,48), valid l3 < 997
// LDS: 13312 + 272 + 7808 + 14080 + 384 = 35856 B.
// __launch_bounds__(256) ONLY — a min-waves hint here caps VGPRs and causes
// catastrophic scratch spill (round 3: VGPR 64, 30 GB HBM spill traffic).
__launch_bounds__(256)
__global__ void conv_fused(const int* __restrict__ seq, const float* __restrict__ emb,
                           const float* __restrict__ ck1, const float* __restrict__ cb1,
                           const float* __restrict__ ck2, const float* __restrict__ cb2,
                           const float* __restrict__ ck3, const float* __restrict__ cb3,
                           float* __restrict__ outmax) {
  __shared__ float s_emb[26 * 128];
  __shared__ int s_tok[68];
  __shared__ float s_c1[61][32];   // row 60 written-zero guard region
  __shared__ float s_c2[55][64];
  __shared__ int s_max[96];

  int tid = threadIdx.x;
  int tile = blockIdx.x;
  int b = blockIdx.y;
  int t0 = tile * 48;

  if (tid < 96) s_max[tid] = 0;
  // embedding table -> LDS (832 float4)
  for (int idx = tid; idx < 26 * 32; idx += 256) {
    ((float4*)s_emb)[idx] = ((const float4*)emb)[idx];
  }
  // token ids (out-of-range -> 0; emb row 0 is the zeroed padding row)
  if (tid < 67) {
    int p = t0 - 6 + tid;
    s_tok[tid] = (p >= 0 && p < SL) ? seq[b * SL + p] : 0;
  }
  __syncthreads();

  // ---- stage 1: conv1  Cin=128 K=4 Cout=32, outputs j in [0,60)
  {
    int co = tid & 31, jg = tid >> 5;
    int tok[11];
#pragma unroll
    for (int r = 0; r < 11; ++r) tok[r] = s_tok[jg * 8 + r];
    float acc[8];
    float bv = cb1[co];
#pragma unroll
    for (int i = 0; i < 8; ++i) acc[i] = bv;
    for (int c4 = 0; c4 < 32; ++c4) {
      float a[11][4];
#pragma unroll
      for (int r = 0; r < 11; ++r) {
        float4 t4 = *(const float4*)&s_emb[tok[r] * 128 + c4 * 4];
        a[r][0] = t4.x; a[r][1] = t4.y; a[r][2] = t4.z; a[r][3] = t4.w;
      }
      const float* wp = ck1 + co * 512 + c4 * 16;  // [co][ci][k], 16 contiguous
#pragma unroll
      for (int cc = 0; cc < 4; ++cc) {
        float4 w4 = *(const float4*)(wp + cc * 4);
        float wk[4] = {w4.x, w4.y, w4.z, w4.w};
#pragma unroll
        for (int k = 0; k < 4; ++k) {
          float wv = wk[k];
#pragma unroll
          for (int i = 0; i < 8; ++i) acc[i] += a[i + k][cc] * wv;
        }
      }
    }
#pragma unroll
    for (int i = 0; i < 8; ++i) {
      int j = jg * 8 + i;
      if (j < 60) {
        int l1 = t0 - 5 + j;
        s_c1[j][co] = (l1 >= 0 && l1 < 999) ? fmaxf(acc[i], 0.f) : 0.f;
      }
    }
  }
  __syncthreads();

  // ---- stage 2: conv2  Cin=32 K=6 Cout=64, outputs j in [0,55)
  {
    int cp = tid & 31, jg = tid >> 5;
    int co0 = cp * 2;
    float acc[7][2];
    {
      float b0 = cb2[co0], b1 = cb2[co0 + 1];
#pragma unroll
      for (int i = 0; i < 7; ++i) { acc[i][0] = b0; acc[i][1] = b1; }
    }
    for (int c4 = 0; c4 < 8; ++c4) {
      float a[12][4];
#pragma unroll
      for (int r = 0; r < 12; ++r) {
        float4 t4 = *(const float4*)&s_c1[jg * 7 + r][c4 * 4];
        a[r][0] = t4.x; a[r][1] = t4.y; a[r][2] = t4.z; a[r][3] = t4.w;
      }
      const float* p0 = ck2 + co0 * 192 + c4 * 24;  // [co][ci][k]
#pragma unroll
      for (int cc = 0; cc < 4; ++cc) {
        float w0[6], w1[6];
#pragma unroll
        for (int q = 0; q < 3; ++q) {
          float2 u0 = *(const float2*)(p0 + cc * 6 + q * 2);
          float2 u1 = *(const float2*)(p0 + 192 + cc * 6 + q * 2);
          w0[q * 2] = u0.x; w0[q * 2 + 1] = u0.y;
          w1[q * 2] = u1.x; w1[q * 2 + 1] = u1.y;
        }
#pragma unroll
        for (int k = 0; k < 6; ++k) {
#pragma unroll
          for (int i = 0; i < 7; ++i) {
            acc[i][0] += a[i + k][cc] * w0[k];
            acc[i][1] += a[i + k][cc] * w1[k];
          }
        }
      }
    }
#pragma unroll
    for (int i = 0; i < 7; ++i) {
      int j = jg * 7 + i;
      if (j < 55) {
        int l2 = t0 - 3 + j;
        bool ok = (l2 >= 0 && l2 < 998);
        s_c2[j][co0] = ok ? fmaxf(acc[i][0], 0.f) : 0.f;
        s_c2[j][co0 + 1] = ok ? fmaxf(acc[i][1], 0.f) : 0.f;
      }
    }
  }
  __syncthreads();

  // ---- stage 3: conv3  Cin=64 K=8 Cout=96, outputs j in [0,48), + relu-max
  {
    int ct = tid & 31, jg = tid >> 5;
    int co0 = ct * 3;
    float acc[6][3];
    {
      float b0 = cb3[co0], b1 = cb3[co0 + 1], b2 = cb3[co0 + 2];
#pragma unroll
      for (int i = 0; i < 6; ++i) { acc[i][0] = b0; acc[i][1] = b1; acc[i][2] = b2; }
    }
    for (int c4 = 0; c4 < 16; ++c4) {
      float a[13][4];
#pragma unroll
      for (int r = 0; r < 13; ++r) {
        float4 t4 = *(const float4*)&s_c2[jg * 6 + r][c4 * 4];
        a[r][0] = t4.x; a[r][1] = t4.y; a[r][2] = t4.z; a[r][3] = t4.w;
      }
#pragma unroll
      for (int t = 0; t < 3; ++t) {
        const float* wp = ck3 + (co0 + t) * 512 + c4 * 32;  // [4cc][8k] chunk
#pragma unroll
        for (int cc = 0; cc < 4; ++cc) {
          float4 wa = *(const float4*)(wp + cc * 8);
          float4 wb = *(const float4*)(wp + cc * 8 + 4);
          float wk[8] = {wa.x, wa.y, wa.z, wa.w, wb.x, wb.y, wb.z, wb.w};
#pragma unroll
          for (int k = 0; k < 8; ++k) {
            float wv = wk[k];
#pragma unroll
            for (int i = 0; i < 6; ++i) acc[i][t] += a[i + k][cc] * wv;
          }
        }
      }
    }
    float m0 = 0.f, m1 = 0.f, m2 = 0.f;  // relu folded into max(0,.)
#pragma unroll
    for (int i = 0; i < 6; ++i) {
      int l3 = t0 + jg * 6 + i;
      if (l3 < 997) {
        m0 = fmaxf(m0, acc[i][0]);
        m1 = fmaxf(m1, acc[i][1]);
        m2 = fmaxf(m2, acc[i][2]);
      }
    }
    atomicMax(&s_max[co0], __float_as_int(m0));
    atomicMax(&s_max[co0 + 1], __float_as_int(m1));
    atomicMax(&s_max[co0 + 2], __float_as_int(m2));
  }
  __syncthreads();
  if (tid < 96) atomicMax((int*)&outmax[b * 224 + 128 + tid], s_max[tid]);
}

// ---------------- final 256 -> 1 ----------------
__global__ void k_fc3(const float* __restrict__ in, const float* __restrict__ w,
                      const float* __restrict__ bias, float* __restrict__ out) {
  int b = blockIdx.x * 256 + threadIdx.x;
  if (b >= NB) return;
  float acc = bias[0];
#pragma unroll 4
  for (int k = 0; k < 256; ++k) acc += in[b * 256 + k] * w[k];
  out[b] = acc;
}

extern "C" void kernel_launch(void* const* d_in, const int* in_sizes, int n_in,
                              void* d_out, int out_size, void* d_ws, size_t ws_size,
                              hipStream_t stream) {
  (void)in_sizes; (void)n_in; (void)out_size; (void)ws_size;
  const float* x = (const float*)d_in[0];
  const int* ei = (const int*)d_in[1];
  const int* batch = (const int*)d_in[2];
  const int* seq = (const int*)d_in[3];
  const float* W1 = (const float*)d_in[4];
  // b1/b2/b3 (d_in[5,9,13]) dropped: constant channel bias cancels in BatchNorm
  const float* g1 = (const float*)d_in[6];
  const float* bt1 = (const float*)d_in[7];
  const float* W2 = (const float*)d_in[8];
  const float* g2 = (const float*)d_in[10];
  const float* bt2 = (const float*)d_in[11];
  const float* W3 = (const float*)d_in[12];
  const float* g3 = (const float*)d_in[14];
  const float* bt3 = (const float*)d_in[15];
  const float* emb = (const float*)d_in[16];
  const float* ck1 = (const float*)d_in[17];
  const float* cb1 = (const float*)d_in[18];
  const float* ck2 = (const float*)d_in[19];
  const float* cb2 = (const float*)d_in[20];
  const float* ck3 = (const float*)d_in[21];
  const float* cb3 = (const float*)d_in[22];
  const float* fw1 = (const float*)d_in[23];
  const float* fb1 = (const float*)d_in[24];
  const float* fw2 = (const float*)d_in[25];
  const float* fb2 = (const float*)d_in[26];
  const float* fw3 = (const float*)d_in[27];
  const float* fb3 = (const float*)d_in[28];
  const int* src = ei;
  const int* dst = ei + NE;

  float* ws = (float*)d_ws;
  float* bufA = ws;                 // 32768*128 (16 MB): agg / h (in-place)
  float* bufB = ws + 4194304;       // 32768*128 (16 MB): xw / fc scratch
  float* dis = ws + 8388608;        // 32768
  float* stats = ws + 8421376;      // 256
  float* cbuf = ws + 8421632;       // 512*224 concat features
  float* cnt2 = ws + 8536320;       // 512
  float* out = (float*)d_out;

  hipMemsetAsync(dis, 0, NN * sizeof(float), stream);
  hipMemsetAsync(cbuf, 0, NB * 224 * sizeof(float), stream);
  hipMemsetAsync(cnt2, 0, NB * sizeof(float), stream);

  k_deg<<<NE / 256, 256, 0, stream>>>(dst, dis, NE);
  k_dis<<<NN / 256, 256, 0, stream>>>(dis, NN);

  // ---- GCN layer 1 (5 -> 64): in=x distinct, so fused self-term is safe
  k_fc<64, 5, false, false, true><<<NN * 16 / 256, 256, 0, stream>>>(x, W1, nullptr, dis, bufB, bufA, NN);
  k_scatter<64><<<NE * 16 / 256, 256, 0, stream>>>(bufB, dis, src, dst, bufA, NE);
  hipMemsetAsync(stats, 0, 128 * sizeof(float), stream);
  k_bnstats<64><<<256, 256, 0, stream>>>(bufA, stats, NN);
  k_bnfinal<64><<<1, 64, 0, stream>>>(stats, g1, bt1, NN);
  k_bnrelu<64><<<NN * 16 / 256, 256, 0, stream>>>(bufA, stats, NN);

  // ---- GCN layer 2 (64 -> 128): in=bufA, so self-term must be a separate pass
  k_fc<128, 64, false, false, false><<<NN * 32 / 256, 256, 0, stream>>>(bufA, W2, nullptr, nullptr, bufB, nullptr, NN);
  k_selfscale<128><<<NN * 32 / 256, 256, 0, stream>>>(bufB, dis, bufA, NN);
  k_scatter<128><<<NE * 32 / 256, 256, 0, stream>>>(bufB, dis, src, dst, bufA, NE);
  hipMemsetAsync(stats, 0, 256 * sizeof(float), stream);
  k_bnstats<128><<<256, 256, 0, stream>>>(bufA, stats, NN);
  k_bnfinal<128><<<1, 128, 0, stream>>>(stats, g2, bt2, NN);
  k_bnrelu<128><<<NN * 32 / 256, 256, 0, stream>>>(bufA, stats, NN);

  // ---- GCN layer 3 (128 -> 128)
  k_fc<128, 128, false, false, false><<<NN * 32 / 256, 256, 0, stream>>>(bufA, W3, nullptr, nullptr, bufB, nullptr, NN);
  k_selfscale<128><<<NN * 32 / 256, 256, 0, stream>>>(bufB, dis, bufA, NN);
  k_scatter<128><<<NE * 32 / 256, 256, 0, stream>>>(bufB, dis, src, dst, bufA, NE);
  hipMemsetAsync(stats, 0, 256 * sizeof(float), stream);
  k_bnstats<128><<<256, 256, 0, stream>>>(bufA, stats, NN);
  k_bnfinal<128><<<1, 128, 0, stream>>>(stats, g3, bt3, NN);
  k_bnrelu<128><<<NN * 32 / 256, 256, 0, stream>>>(bufA, stats, NN);

  // ---- graph mean pool -> cbuf[:, 0:128]
  k_pool<<<NN * 32 / 256, 256, 0, stream>>>(bufA, batch, cbuf, cnt2, NN);
  k_pooldiv<<<NB * 128 / 256, 256, 0, stream>>>(cbuf, cnt2);

  // ---- protein encoder -> cbuf[:, 128:224]
  conv_fused<<<dim3(21, NB), 256, 0, stream>>>(seq, emb, ck1, cb1, ck2, cb2, ck3, cb3, cbuf);

  // ---- regressor
  k_fc<512, 224, true, true, false><<<NB * 128 / 256, 256, 0, stream>>>(cbuf, fw1, fb1, nullptr, bufB, nullptr, NB);
  k_fc<256, 512, true, true, false><<<NB * 64 / 256, 256, 0, stream>>>(bufB, fw2, fb2, nullptr, bufA, nullptr, NB);
  k_fc3<<<2, 256, 0, stream>>>(bufA, fw3, fb3, out);
}

// Round 5
// 1535.776 us; speedup vs baseline: 5.3713x; 2.6755x over previous
//
#include <hip/hip_runtime.h>

#define NN 32768
#define NE 131072
#define NB 512
#define SL 1000

using bf16x8 = __attribute__((ext_vector_type(8))) short;
using f32x4  = __attribute__((ext_vector_type(4))) float;

static __device__ __forceinline__ unsigned short f2b(float f) {
  union { float f; unsigned u; } x; x.f = f;
  unsigned r = x.u + 0x7fffu + ((x.u >> 16) & 1u);  // RNE
  return (unsigned short)(r >> 16);
}

// ---------------- degree / normalization ----------------
__global__ void k_deg(const int* __restrict__ dst, float* __restrict__ deg, int E) {
  int e = blockIdx.x * 256 + threadIdx.x;
  if (e < E) atomicAdd(&deg[dst[e]], 1.0f);
}
__global__ void k_dis(float* d, int N) {
  int i = blockIdx.x * 256 + threadIdx.x;
  if (i < N) d[i] = rsqrtf(1.0f + d[i]);
}

// ---------------- weight prep: fp32 [co][ci][k] -> bf16 [k][co][ci]; emb -> bf16 ----------------
__global__ void k_prep(const float* __restrict__ emb, const float* __restrict__ ck1,
                       const float* __restrict__ ck2, const float* __restrict__ ck3,
                       unsigned short* __restrict__ emb_bf, unsigned short* __restrict__ wt1,
                       unsigned short* __restrict__ wt2, unsigned short* __restrict__ wt3) {
  int idx = blockIdx.x * 256 + threadIdx.x;
  if (idx < 3328) {                       // emb 26x128
    emb_bf[idx] = f2b(emb[idx]);
  } else if (idx < 3328 + 16384) {        // wt1[k<4][co<32][ci<128]
    int i = idx - 3328;
    int kt = i >> 12, co = (i >> 7) & 31, ci = i & 127;
    wt1[i] = f2b(ck1[co * 512 + ci * 4 + kt]);
  } else if (idx < 3328 + 16384 + 12288) { // wt2[k<6][co<64][ci<32]
    int i = idx - 3328 - 16384;
    int kt = i >> 11, co = (i >> 5) & 63, ci = i & 31;
    wt2[i] = f2b(ck2[co * 192 + ci * 6 + kt]);
  } else if (idx < 3328 + 16384 + 12288 + 49152) { // wt3[k<8][co<96][ci<64]
    int i = idx - 3328 - 16384 - 12288;
    int kt = i / 6144, co = (i >> 6) % 96, ci = i & 63;
    wt3[i] = f2b(ck3[co * 512 + ci * 8 + kt]);
  }
}

// ---------------- generic dense layer (fp32, GNN xw + regressor) ----------------
template<int C_OUT, int K, bool RELU, bool BIAS, bool SELF>
__launch_bounds__(256)
__global__ void k_fc(const float* __restrict__ in, const float* __restrict__ W,
                     const float* __restrict__ bias, const float* __restrict__ dis,
                     float* __restrict__ out, float* __restrict__ out2, int N) {
  constexpr int CO4 = C_OUT / 4;
  int gid = blockIdx.x * 256 + threadIdx.x;
  int n = gid / CO4;
  if (n >= N) return;
  int co = (gid - n * CO4) * 4;
  const float* row = in + (long)n * K;
  float ax = 0.f, ay = 0.f, az = 0.f, aw = 0.f;
  if (BIAS) {
    float4 b4 = *(const float4*)&bias[co];
    ax = b4.x; ay = b4.y; az = b4.z; aw = b4.w;
  }
#pragma unroll 4
  for (int ci = 0; ci < K; ++ci) {
    float a = row[ci];
    float4 w = *(const float4*)&W[(long)ci * C_OUT + co];
    ax += a * w.x; ay += a * w.y; az += a * w.z; aw += a * w.w;
  }
  if (RELU) {
    ax = fmaxf(ax, 0.f); ay = fmaxf(ay, 0.f); az = fmaxf(az, 0.f); aw = fmaxf(aw, 0.f);
  }
  float4 o; o.x = ax; o.y = ay; o.z = az; o.w = aw;
  *(float4*)&out[(long)n * C_OUT + co] = o;
  if (SELF) {
    float s = dis[n]; s = s * s;
    float4 o2; o2.x = ax * s; o2.y = ay * s; o2.z = az * s; o2.w = aw * s;
    *(float4*)&out2[(long)n * C_OUT + co] = o2;
  }
}

// ---------------- GCN self-loop term ----------------
template<int C>
__global__ void k_selfscale(const float* __restrict__ xw, const float* __restrict__ dis,
                            float* __restrict__ agg, int N) {
  constexpr int C4 = C / 4;
  int gid = blockIdx.x * 256 + threadIdx.x;
  int n = gid / C4;
  if (n >= N) return;
  int c = (gid - n * C4) * 4;
  float s = dis[n]; s = s * s;
  float4 v = *(const float4*)&xw[(long)n * C + c];
  v.x *= s; v.y *= s; v.z *= s; v.w *= s;
  *(float4*)&agg[(long)n * C + c] = v;
}

// ---------------- edge scatter ----------------
template<int C>
__global__ void k_scatter(const float* __restrict__ xw, const float* __restrict__ dis,
                          const int* __restrict__ src, const int* __restrict__ dst,
                          float* __restrict__ agg, int E) {
  constexpr int C4 = C / 4;
  int gid = blockIdx.x * 256 + threadIdx.x;
  int e = gid / C4;
  if (e >= E) return;
  int c = (gid - e * C4) * 4;
  int s = src[e], d = dst[e];
  float coef = dis[s] * dis[d];
  float4 v = *(const float4*)&xw[(long)s * C + c];
  float* p = &agg[(long)d * C + c];
  atomicAdd(p + 0, v.x * coef);
  atomicAdd(p + 1, v.y * coef);
  atomicAdd(p + 2, v.z * coef);
  atomicAdd(p + 3, v.w * coef);
}

// ---------------- batchnorm ----------------
template<int C>
__global__ void k_bnstats(const float* __restrict__ h, float* __restrict__ stats, int N) {
  constexpr int RPB = 256 / C;
  int c = threadIdx.x % C;
  int r = threadIdx.x / C;
  float s = 0.f, ss = 0.f;
  for (int n = blockIdx.x * RPB + r; n < N; n += gridDim.x * RPB) {
    float v = h[(long)n * C + c];
    s += v; ss += v * v;
  }
  __shared__ float ls[256], lss[256];
  ls[threadIdx.x] = s; lss[threadIdx.x] = ss;
  __syncthreads();
  if (threadIdx.x < C) {
    float st = 0.f, sst = 0.f;
#pragma unroll
    for (int r2 = 0; r2 < RPB; ++r2) { st += ls[c + r2 * C]; sst += lss[c + r2 * C]; }
    atomicAdd(&stats[c], st);
    atomicAdd(&stats[C + c], sst);
  }
}

template<int C>
__global__ void k_bnfinal(float* stats, const float* __restrict__ g,
                          const float* __restrict__ bt, int N) {
  int c = threadIdx.x;
  float m = stats[c] / (float)N;
  float v = stats[C + c] / (float)N - m * m;
  float sc = g[c] * rsqrtf(v + 1e-5f);
  stats[c] = sc;
  stats[C + c] = bt[c] - m * sc;
}

template<int C>
__global__ void k_bnrelu(float* __restrict__ h, const float* __restrict__ stats, int N) {
  constexpr int C4 = C / 4;
  int gid = blockIdx.x * 256 + threadIdx.x;
  int n = gid / C4;
  if (n >= N) return;
  int c = (gid - n * C4) * 4;
  float4 v = *(float4*)&h[(long)n * C + c];
  float4 sc = *(const float4*)&stats[c];
  float4 sh = *(const float4*)&stats[C + c];
  v.x = fmaxf(v.x * sc.x + sh.x, 0.f);
  v.y = fmaxf(v.y * sc.y + sh.y, 0.f);
  v.z = fmaxf(v.z * sc.z + sh.z, 0.f);
  v.w = fmaxf(v.w * sc.w + sh.w, 0.f);
  *(float4*)&h[(long)n * C + c] = v;
}

// ---------------- graph mean-pool: batch[] is sorted -> per-b range by binary search ----------------
__global__ void k_pool2(const float* __restrict__ h, const int* __restrict__ batch,
                        float* __restrict__ cbuf) {
  int b = blockIdx.x;
  __shared__ int s_lo, s_hi;
  if (threadIdx.x == 0) {
    int lo = 0, hi = NN;
    while (lo < hi) { int m = (lo + hi) >> 1; if (batch[m] < b) lo = m + 1; else hi = m; }
    s_lo = lo;
    hi = NN;
    while (lo < hi) { int m = (lo + hi) >> 1; if (batch[m] <= b) lo = m + 1; else hi = m; }
    s_hi = lo;
  }
  __syncthreads();
  int lo = s_lo, hi = s_hi;
  int c = threadIdx.x;  // 128 threads = 128 channels
  float s = 0.f;
  for (int n = lo; n < hi; ++n) s += h[(long)n * 128 + c];
  cbuf[b * 224 + c] = s / fmaxf((float)(hi - lo), 1.0f);
}

// ---------------- protein encoder: bf16 MFMA implicit GEMM ----------------
// Block = (tile of 64 conv3 outputs, batch b). 4 waves. 16x16x32 bf16 MFMA.
// Position chains (all array rows indexed i = pos - base):
//   s_in rows 84: p  = t0-6+i   ;  conv1 A row = m + kt (m = l1 - (t0-5))
//   s_c1 rows 85: l1 = t0-5+i   ;  conv2 A row = m + kt (m = l2 - (t0-3))
//   s_c2 rows 80: l2 = t0-3+i   ;  conv3 A row = m + kt (m = l3 - t0)
// conv1: M=80 (5 mt), N=32 (2 nt), K=512 (4 kt x 4 cb of 32)
// conv2: M=80 (5 mt), N=64 (4 nt), K=192 (6 kt)
// conv3: M=64 (4 mt), N=96 (6 nt), K=512 (8 kt x 2 cb)
// Rows are padded +8 bf16 so all row strides are 16B-multiples (b128-aligned).
// Validity masks: l1<999, l2<998 zero-written; l3<997 masked in max epilogue.
// s_c1 rows 80..84 are read by mt=4 garbage outputs only -> zeroed for finiteness.
// NOTE: plain __launch_bounds__(256); min-waves hint causes scratch spill (round 3).
__launch_bounds__(256)
__global__ void conv_mfma(const int* __restrict__ seq, const unsigned short* __restrict__ emb_bf,
                          const unsigned short* __restrict__ wt1, const float* __restrict__ cb1,
                          const unsigned short* __restrict__ wt2, const float* __restrict__ cb2,
                          const unsigned short* __restrict__ wt3, const float* __restrict__ cb3,
                          float* __restrict__ outmax) {
  __shared__ __align__(16) unsigned short s_in[84][136];
  __shared__ __align__(16) unsigned short s_c1[85][40];
  __shared__ __align__(16) unsigned short s_c2[80][72];
  __shared__ int s_tok[84];
  __shared__ int s_max[96];

  int tid = threadIdx.x;
  int t0 = blockIdx.x * 64;
  int b = blockIdx.y;

  if (tid < 96) s_max[tid] = 0;
  if (tid < 84) {
    int p = t0 - 6 + tid;
    s_tok[tid] = (p >= 0 && p < SL) ? seq[b * SL + p] : 0;  // tok 0 row is all-zero
  }
  if (tid < 100) ((int*)&s_c1[80][0])[tid] = 0;  // 5 tail rows x 40 ushort = 100 ints
  __syncthreads();

  // stage embeddings: 84 rows x 16 chunks of 8 bf16
  for (int u = tid; u < 84 * 16; u += 256) {
    int row = u >> 4, ch = u & 15;
    bf16x8 v = *(const bf16x8*)(emb_bf + s_tok[row] * 128 + ch * 8);
    *(bf16x8*)&s_in[row][ch * 8] = v;
  }
  __syncthreads();

  int lane = tid & 63, wave = tid >> 6;
  int l15 = lane & 15, quad = lane >> 4;

  // ---- conv1
  for (int mt = wave; mt < 5; mt += 4) {
    f32x4 acc[2];
#pragma unroll
    for (int nt = 0; nt < 2; ++nt) {
      float bv = cb1[nt * 16 + l15];
      acc[nt] = (f32x4){bv, bv, bv, bv};
    }
    for (int kt = 0; kt < 4; ++kt) {
      int arow = mt * 16 + l15 + kt;
#pragma unroll
      for (int cb = 0; cb < 4; ++cb) {
        bf16x8 a = *(const bf16x8*)&s_in[arow][cb * 32 + quad * 8];
#pragma unroll
        for (int nt = 0; nt < 2; ++nt) {
          bf16x8 bf = *(const bf16x8*)(wt1 + (kt * 32 + nt * 16 + l15) * 128 + cb * 32 + quad * 8);
          acc[nt] = __builtin_amdgcn_mfma_f32_16x16x32_bf16(a, bf, acc[nt], 0, 0, 0);
        }
      }
    }
#pragma unroll
    for (int nt = 0; nt < 2; ++nt) {
      int co = nt * 16 + l15;
#pragma unroll
      for (int r = 0; r < 4; ++r) {
        int m = mt * 16 + quad * 4 + r;
        int l1 = t0 - 5 + m;
        unsigned short hv = f2b(fmaxf(acc[nt][r], 0.f));
        s_c1[m][co] = (l1 >= 0 && l1 < 999) ? hv : (unsigned short)0;
      }
    }
  }
  __syncthreads();

  // ---- conv2
  for (int mt = wave; mt < 5; mt += 4) {
    f32x4 acc[4];
#pragma unroll
    for (int nt = 0; nt < 4; ++nt) {
      float bv = cb2[nt * 16 + l15];
      acc[nt] = (f32x4){bv, bv, bv, bv};
    }
    for (int kt = 0; kt < 6; ++kt) {
      bf16x8 a = *(const bf16x8*)&s_c1[mt * 16 + l15 + kt][quad * 8];
#pragma unroll
      for (int nt = 0; nt < 4; ++nt) {
        bf16x8 bf = *(const bf16x8*)(wt2 + (kt * 64 + nt * 16 + l15) * 32 + quad * 8);
        acc[nt] = __builtin_amdgcn_mfma_f32_16x16x32_bf16(a, bf, acc[nt], 0, 0, 0);
      }
    }
#pragma unroll
    for (int nt = 0; nt < 4; ++nt) {
      int co = nt * 16 + l15;
#pragma unroll
      for (int r = 0; r < 4; ++r) {
        int m = mt * 16 + quad * 4 + r;
        int l2 = t0 - 3 + m;
        unsigned short hv = f2b(fmaxf(acc[nt][r], 0.f));
        s_c2[m][co] = (l2 >= 0 && l2 < 998) ? hv : (unsigned short)0;
      }
    }
  }
  __syncthreads();

  // ---- conv3 + relu-max epilogue
  {
    int mt = wave;
    f32x4 acc[6];
#pragma unroll
    for (int nt = 0; nt < 6; ++nt) {
      float bv = cb3[nt * 16 + l15];
      acc[nt] = (f32x4){bv, bv, bv, bv};
    }
    for (int kt = 0; kt < 8; ++kt) {
      int arow = mt * 16 + l15 + kt;
#pragma unroll
      for (int cb = 0; cb < 2; ++cb) {
        bf16x8 a = *(const bf16x8*)&s_c2[arow][cb * 32 + quad * 8];
#pragma unroll
        for (int nt = 0; nt < 6; ++nt) {
          bf16x8 bf = *(const bf16x8*)(wt3 + (kt * 96 + nt * 16 + l15) * 64 + cb * 32 + quad * 8);
          acc[nt] = __builtin_amdgcn_mfma_f32_16x16x32_bf16(a, bf, acc[nt], 0, 0, 0);
        }
      }
    }
#pragma unroll
    for (int nt = 0; nt < 6; ++nt) {
      float mx = 0.f;  // relu folded: max(0, .)
#pragma unroll
      for (int r = 0; r < 4; ++r) {
        int l3 = t0 + mt * 16 + quad * 4 + r;
        if (l3 < 997) mx = fmaxf(mx, acc[nt][r]);
      }
      atomicMax(&s_max[nt * 16 + l15], __float_as_int(mx));
    }
  }
  __syncthreads();
  if (tid < 96) atomicMax((int*)&outmax[b * 224 + 128 + tid], s_max[tid]);
}

// ---------------- final 256 -> 1 ----------------
__global__ void k_fc3(const float* __restrict__ in, const float* __restrict__ w,
                      const float* __restrict__ bias, float* __restrict__ out) {
  int b = blockIdx.x * 256 + threadIdx.x;
  if (b >= NB) return;
  float acc = bias[0];
#pragma unroll 4
  for (int k = 0; k < 256; ++k) acc += in[b * 256 + k] * w[k];
  out[b] = acc;
}

extern "C" void kernel_launch(void* const* d_in, const int* in_sizes, int n_in,
                              void* d_out, int out_size, void* d_ws, size_t ws_size,
                              hipStream_t stream) {
  (void)in_sizes; (void)n_in; (void)out_size; (void)ws_size;
  const float* x = (const float*)d_in[0];
  const int* ei = (const int*)d_in[1];
  const int* batch = (const int*)d_in[2];
  const int* seq = (const int*)d_in[3];
  const float* W1 = (const float*)d_in[4];
  // b1/b2/b3 (d_in[5,9,13]) dropped: constant channel bias cancels in BatchNorm
  const float* g1 = (const float*)d_in[6];
  const float* bt1 = (const float*)d_in[7];
  const float* W2 = (const float*)d_in[8];
  const float* g2 = (const float*)d_in[10];
  const float* bt2 = (const float*)d_in[11];
  const float* W3 = (const float*)d_in[12];
  const float* g3 = (const float*)d_in[14];
  const float* bt3 = (const float*)d_in[15];
  const float* emb = (const float*)d_in[16];
  const float* ck1 = (const float*)d_in[17];
  const float* cb1 = (const float*)d_in[18];
  const float* ck2 = (const float*)d_in[19];
  const float* cb2 = (const float*)d_in[20];
  const float* ck3 = (const float*)d_in[21];
  const float* cb3 = (const float*)d_in[22];
  const float* fw1 = (const float*)d_in[23];
  const float* fb1 = (const float*)d_in[24];
  const float* fw2 = (const float*)d_in[25];
  const float* fb2 = (const float*)d_in[26];
  const float* fw3 = (const float*)d_in[27];
  const float* fb3 = (const float*)d_in[28];
  const int* src = ei;
  const int* dst = ei + NE;

  float* ws = (float*)d_ws;
  float* bufA = ws;                 // 32768*128 (16 MB)
  float* bufB = ws + 4194304;       // 32768*128 (16 MB)
  float* dis = ws + 8388608;        // 32768
  float* stats = ws + 8421376;      // 256
  float* cbuf = ws + 8421632;       // 512*224
  // bf16 area (float offset 8536832 = byte 34147328)
  unsigned short* emb_bf = (unsigned short*)(ws + 8536832);  // 3328
  unsigned short* wt1 = emb_bf + 3328;                       // 16384
  unsigned short* wt2 = wt1 + 16384;                         // 12288
  unsigned short* wt3 = wt2 + 12288;                         // 49152
  float* out = (float*)d_out;

  hipMemsetAsync(dis, 0, NN * sizeof(float), stream);
  hipMemsetAsync(cbuf, 0, NB * 224 * sizeof(float), stream);

  k_prep<<<318, 256, 0, stream>>>(emb, ck1, ck2, ck3, emb_bf, wt1, wt2, wt3);
  k_deg<<<NE / 256, 256, 0, stream>>>(dst, dis, NE);
  k_dis<<<NN / 256, 256, 0, stream>>>(dis, NN);

  // ---- GCN layer 1 (5 -> 64): in=x distinct, fused self-term safe
  k_fc<64, 5, false, false, true><<<NN * 16 / 256, 256, 0, stream>>>(x, W1, nullptr, dis, bufB, bufA, NN);
  k_scatter<64><<<NE * 16 / 256, 256, 0, stream>>>(bufB, dis, src, dst, bufA, NE);
  hipMemsetAsync(stats, 0, 128 * sizeof(float), stream);
  k_bnstats<64><<<256, 256, 0, stream>>>(bufA, stats, NN);
  k_bnfinal<64><<<1, 64, 0, stream>>>(stats, g1, bt1, NN);
  k_bnrelu<64><<<NN * 16 / 256, 256, 0, stream>>>(bufA, stats, NN);

  // ---- GCN layer 2 (64 -> 128): in aliases h -> separate self pass
  k_fc<128, 64, false, false, false><<<NN * 32 / 256, 256, 0, stream>>>(bufA, W2, nullptr, nullptr, bufB, nullptr, NN);
  k_selfscale<128><<<NN * 32 / 256, 256, 0, stream>>>(bufB, dis, bufA, NN);
  k_scatter<128><<<NE * 32 / 256, 256, 0, stream>>>(bufB, dis, src, dst, bufA, NE);
  hipMemsetAsync(stats, 0, 256 * sizeof(float), stream);
  k_bnstats<128><<<256, 256, 0, stream>>>(bufA, stats, NN);
  k_bnfinal<128><<<1, 128, 0, stream>>>(stats, g2, bt2, NN);
  k_bnrelu<128><<<NN * 32 / 256, 256, 0, stream>>>(bufA, stats, NN);

  // ---- GCN layer 3 (128 -> 128)
  k_fc<128, 128, false, false, false><<<NN * 32 / 256, 256, 0, stream>>>(bufA, W3, nullptr, nullptr, bufB, nullptr, NN);
  k_selfscale<128><<<NN * 32 / 256, 256, 0, stream>>>(bufB, dis, bufA, NN);
  k_scatter<128><<<NE * 32 / 256, 256, 0, stream>>>(bufB, dis, src, dst, bufA, NE);
  hipMemsetAsync(stats, 0, 256 * sizeof(float), stream);
  k_bnstats<128><<<256, 256, 0, stream>>>(bufA, stats, NN);
  k_bnfinal<128><<<1, 128, 0, stream>>>(stats, g3, bt3, NN);
  k_bnrelu<128><<<NN * 32 / 256, 256, 0, stream>>>(bufA, stats, NN);

  // ---- graph mean pool (sorted batch, no atomics) -> cbuf[:, 0:128]
  k_pool2<<<NB, 128, 0, stream>>>(bufA, batch, cbuf);

  // ---- protein encoder -> cbuf[:, 128:224]
  conv_mfma<<<dim3(16, NB), 256, 0, stream>>>(seq, emb_bf, wt1, cb1, wt2, cb2, wt3, cb3, cbuf);

  // ---- regressor
  k_fc<512, 224, true, true, false><<<NB * 128 / 256, 256, 0, stream>>>(cbuf, fw1, fb1, nullptr, bufB, nullptr, NB);
  k_fc<256, 512, true, true, false><<<NB * 64 / 256, 256, 0, stream>>>(bufB, fw2, fb2, nullptr, bufA, nullptr, NB);
  k_fc3<<<2, 256, 0, stream>>>(bufA, fw3, fb3, out);
}

// Round 6
// 1123.096 us; speedup vs baseline: 7.3450x; 1.3674x over previous
//
#include <hip/hip_runtime.h>

#define NN 32768
#define NE 131072
#define NB 512
#define SL 1000

using bf16x8 = __attribute__((ext_vector_type(8))) short;
using f32x4  = __attribute__((ext_vector_type(4))) float;

static __device__ __forceinline__ unsigned short f2b(float f) {
  union { float f; unsigned u; } x; x.f = f;
  unsigned r = x.u + 0x7fffu + ((x.u >> 16) & 1u);  // RNE
  return (unsigned short)(r >> 16);
}

// ---------------- degree (int) / normalization ----------------
__global__ void k_degi(const int* __restrict__ dst, int* __restrict__ degi, int E) {
  int e = blockIdx.x * 256 + threadIdx.x;
  if (e < E) atomicAdd(&degi[dst[e]], 1);
}
__global__ void k_dis2(const int* __restrict__ degi, float* __restrict__ dis, int N) {
  int i = blockIdx.x * 256 + threadIdx.x;
  if (i < N) dis[i] = rsqrtf(1.0f + (float)degi[i]);
}

// ---------------- CSR build: scan (1 block) + fill ----------------
__global__ void k_scan(const int* __restrict__ degi, int* __restrict__ base,
                       int* __restrict__ cursor) {
  __shared__ int part[1024];
  int tid = threadIdx.x;
  int v[32];
  int s = 0;
  int lo = tid * 32;
#pragma unroll
  for (int i = 0; i < 32; ++i) { v[i] = degi[lo + i]; s += v[i]; }
  part[tid] = s;
  __syncthreads();
  for (int off = 1; off < 1024; off <<= 1) {
    int val = (tid >= off) ? part[tid - off] : 0;
    __syncthreads();
    part[tid] += val;
    __syncthreads();
  }
  int run = (tid > 0) ? part[tid - 1] : 0;
#pragma unroll
  for (int i = 0; i < 32; ++i) {
    base[lo + i] = run;
    cursor[lo + i] = run;
    run += v[i];
  }
  if (tid == 1023) base[NN] = run;
}

__global__ void k_fill(const int* __restrict__ src, const int* __restrict__ dst,
                       int* __restrict__ cursor, unsigned short* __restrict__ csr_src, int E) {
  int e = blockIdx.x * 256 + threadIdx.x;
  if (e < E) {
    int d = dst[e];
    int pos = atomicAdd(&cursor[d], 1);
    csr_src[pos] = (unsigned short)src[e];  // node ids < 32768 fit in u16
  }
}

// ---------------- GCN aggregate (gather, incl. self-loop term) ----------------
// agg[n][c] = xw[n][c]*dis[n]^2 + sum_{e: dst=n} xw[src][c]*dis[src]*dis[n]
template<int C>
__global__ void k_gather(const float* __restrict__ xw, const float* __restrict__ dis,
                         const int* __restrict__ base, const unsigned short* __restrict__ csr_src,
                         float* __restrict__ agg, int N) {
  constexpr int NPB = 256 / C;
  int n = blockIdx.x * NPB + threadIdx.x / C;
  if (n >= N) return;
  int c = threadIdx.x & (C - 1);
  float dn = dis[n];
  float acc = xw[(long)n * C + c] * dn * dn;
  int b0 = base[n], b1 = base[n + 1];
  for (int j = b0; j < b1; ++j) {
    int s = csr_src[j];
    acc += xw[(long)s * C + c] * (dis[s] * dn);
  }
  agg[(long)n * C + c] = acc;
}

// ---------------- weight prep: fp32 [co][ci][k] -> bf16 [k][co][ci]; emb -> bf16 ----------------
__global__ void k_prep(const float* __restrict__ emb, const float* __restrict__ ck1,
                       const float* __restrict__ ck2, const float* __restrict__ ck3,
                       unsigned short* __restrict__ emb_bf, unsigned short* __restrict__ wt1,
                       unsigned short* __restrict__ wt2, unsigned short* __restrict__ wt3) {
  int idx = blockIdx.x * 256 + threadIdx.x;
  if (idx < 3328) {                       // emb 26x128
    emb_bf[idx] = f2b(emb[idx]);
  } else if (idx < 3328 + 16384) {        // wt1[k<4][co<32][ci<128]
    int i = idx - 3328;
    int kt = i >> 12, co = (i >> 7) & 31, ci = i & 127;
    wt1[i] = f2b(ck1[co * 512 + ci * 4 + kt]);
  } else if (idx < 3328 + 16384 + 12288) { // wt2[k<6][co<64][ci<32]
    int i = idx - 3328 - 16384;
    int kt = i >> 11, co = (i >> 5) & 63, ci = i & 31;
    wt2[i] = f2b(ck2[co * 192 + ci * 6 + kt]);
  } else if (idx < 3328 + 16384 + 12288 + 49152) { // wt3[k<8][co<96][ci<64]
    int i = idx - 3328 - 16384 - 12288;
    int kt = i / 6144, co = (i >> 6) % 96, ci = i & 63;
    wt3[i] = f2b(ck3[co * 512 + ci * 8 + kt]);
  }
}

// ---------------- generic dense layer (fp32, GNN xw + regressor) ----------------
template<int C_OUT, int K, bool RELU, bool BIAS>
__launch_bounds__(256)
__global__ void k_fc(const float* __restrict__ in, const float* __restrict__ W,
                     const float* __restrict__ bias, float* __restrict__ out, int N) {
  constexpr int CO4 = C_OUT / 4;
  int gid = blockIdx.x * 256 + threadIdx.x;
  int n = gid / CO4;
  if (n >= N) return;
  int co = (gid - n * CO4) * 4;
  const float* row = in + (long)n * K;
  float ax = 0.f, ay = 0.f, az = 0.f, aw = 0.f;
  if (BIAS) {
    float4 b4 = *(const float4*)&bias[co];
    ax = b4.x; ay = b4.y; az = b4.z; aw = b4.w;
  }
#pragma unroll 4
  for (int ci = 0; ci < K; ++ci) {
    float a = row[ci];
    float4 w = *(const float4*)&W[(long)ci * C_OUT + co];
    ax += a * w.x; ay += a * w.y; az += a * w.z; aw += a * w.w;
  }
  if (RELU) {
    ax = fmaxf(ax, 0.f); ay = fmaxf(ay, 0.f); az = fmaxf(az, 0.f); aw = fmaxf(aw, 0.f);
  }
  float4 o; o.x = ax; o.y = ay; o.z = az; o.w = aw;
  *(float4*)&out[(long)n * C_OUT + co] = o;
}

// ---------------- batchnorm ----------------
template<int C>
__global__ void k_bnstats(const float* __restrict__ h, float* __restrict__ stats, int N) {
  constexpr int RPB = 256 / C;
  int c = threadIdx.x % C;
  int r = threadIdx.x / C;
  float s = 0.f, ss = 0.f;
  for (int n = blockIdx.x * RPB + r; n < N; n += gridDim.x * RPB) {
    float v = h[(long)n * C + c];
    s += v; ss += v * v;
  }
  __shared__ float ls[256], lss[256];
  ls[threadIdx.x] = s; lss[threadIdx.x] = ss;
  __syncthreads();
  if (threadIdx.x < C) {
    float st = 0.f, sst = 0.f;
#pragma unroll
    for (int r2 = 0; r2 < RPB; ++r2) { st += ls[c + r2 * C]; sst += lss[c + r2 * C]; }
    atomicAdd(&stats[c], st);
    atomicAdd(&stats[C + c], sst);
  }
}

template<int C>
__global__ void k_bnfinal(float* stats, const float* __restrict__ g,
                          const float* __restrict__ bt, int N) {
  int c = threadIdx.x;
  float m = stats[c] / (float)N;
  float v = stats[C + c] / (float)N - m * m;
  float sc = g[c] * rsqrtf(v + 1e-5f);
  stats[c] = sc;
  stats[C + c] = bt[c] - m * sc;
}

template<int C>
__global__ void k_bnrelu(float* __restrict__ h, const float* __restrict__ stats, int N) {
  constexpr int C4 = C / 4;
  int gid = blockIdx.x * 256 + threadIdx.x;
  int n = gid / C4;
  if (n >= N) return;
  int c = (gid - n * C4) * 4;
  float4 v = *(float4*)&h[(long)n * C + c];
  float4 sc = *(const float4*)&stats[c];
  float4 sh = *(const float4*)&stats[C + c];
  v.x = fmaxf(v.x * sc.x + sh.x, 0.f);
  v.y = fmaxf(v.y * sc.y + sh.y, 0.f);
  v.z = fmaxf(v.z * sc.z + sh.z, 0.f);
  v.w = fmaxf(v.w * sc.w + sh.w, 0.f);
  *(float4*)&h[(long)n * C + c] = v;
}

// ---------------- graph mean-pool (sorted batch -> binary search ranges) ----------------
__global__ void k_pool2(const float* __restrict__ h, const int* __restrict__ batch,
                        float* __restrict__ cbuf) {
  int b = blockIdx.x;
  __shared__ int s_lo, s_hi;
  if (threadIdx.x == 0) {
    int lo = 0, hi = NN;
    while (lo < hi) { int m = (lo + hi) >> 1; if (batch[m] < b) lo = m + 1; else hi = m; }
    s_lo = lo;
    hi = NN;
    while (lo < hi) { int m = (lo + hi) >> 1; if (batch[m] <= b) lo = m + 1; else hi = m; }
    s_hi = lo;
  }
  __syncthreads();
  int lo = s_lo, hi = s_hi;
  int c = threadIdx.x;  // 128 threads = 128 channels
  float s = 0.f;
  for (int n = lo; n < hi; ++n) s += h[(long)n * 128 + c];
  cbuf[b * 224 + c] = s / fmaxf((float)(hi - lo), 1.0f);
}

// ---------------- protein encoder: bf16 MFMA implicit GEMM ----------------
// Block = (tile of 64 conv3 outputs, batch b). 4 waves. 16x16x32 bf16 MFMA.
// conv1 A-fragments read emb_bf (6.5 KB, L1-resident) directly via s_tok — no
// s_in staging (round 5: 22.8 KB LDS capped occupancy at 3 blocks/CU).
//   tokens idx i: p  = t0-6+i,  i in [0,84)
//   s_c1 row m:   l1 = t0-5+m;  conv2 A row = m + kt (m = l2 - (t0-3))
//   s_c2 row m:   l2 = t0-3+m;  conv3 A row = m + kt (m = l3 - t0)
// conv1: M=80 (5 mt), N=32 (2 nt), K=512 (4 kt x 4 cb of 32)
// conv2: M=80 (5 mt), N=64 (4 nt), K=192 (6 kt)
// conv3: M=64 (4 mt), N=96 (6 nt), K=512 (8 kt x 2 cb)
// Validity: l1<999, l2<998 zero-written; l3<997 masked in max epilogue.
// s_c1 rows 80..84 feed only discarded mt=4 outputs -> zeroed for finiteness.
// LDS ~19 KB. Plain __launch_bounds__(256): min-waves hint => scratch spill (r3).
__launch_bounds__(256)
__global__ void conv_mfma(const int* __restrict__ seq, const unsigned short* __restrict__ emb_bf,
                          const unsigned short* __restrict__ wt1, const float* __restrict__ cb1,
                          const unsigned short* __restrict__ wt2, const float* __restrict__ cb2,
                          const unsigned short* __restrict__ wt3, const float* __restrict__ cb3,
                          float* __restrict__ outmax) {
  __shared__ __align__(16) unsigned short s_c1[85][40];
  __shared__ __align__(16) unsigned short s_c2[80][72];
  __shared__ int s_tok[84];
  __shared__ int s_max[96];

  int tid = threadIdx.x;
  int t0 = blockIdx.x * 64;
  int b = blockIdx.y;

  if (tid < 96) s_max[tid] = 0;
  if (tid < 84) {
    int p = t0 - 6 + tid;
    s_tok[tid] = (p >= 0 && p < SL) ? seq[b * SL + p] : 0;  // tok 0 row is all-zero
  }
  if (tid < 100) ((int*)&s_c1[80][0])[tid] = 0;  // 5 tail rows x 40 ushort
  __syncthreads();

  int lane = tid & 63, wave = tid >> 6;
  int l15 = lane & 15, quad = lane >> 4;

  // ---- conv1 (A direct from emb_bf via tokens)
  for (int mt = wave; mt < 5; mt += 4) {
    f32x4 acc[2];
#pragma unroll
    for (int nt = 0; nt < 2; ++nt) {
      float bv = cb1[nt * 16 + l15];
      acc[nt] = (f32x4){bv, bv, bv, bv};
    }
    for (int kt = 0; kt < 4; ++kt) {
      int tok = s_tok[mt * 16 + l15 + kt];
      const unsigned short* erow = emb_bf + tok * 128 + quad * 8;
#pragma unroll
      for (int cb = 0; cb < 4; ++cb) {
        bf16x8 a = *(const bf16x8*)(erow + cb * 32);
#pragma unroll
        for (int nt = 0; nt < 2; ++nt) {
          bf16x8 bf = *(const bf16x8*)(wt1 + (kt * 32 + nt * 16 + l15) * 128 + cb * 32 + quad * 8);
          acc[nt] = __builtin_amdgcn_mfma_f32_16x16x32_bf16(a, bf, acc[nt], 0, 0, 0);
        }
      }
    }
#pragma unroll
    for (int nt = 0; nt < 2; ++nt) {
      int co = nt * 16 + l15;
#pragma unroll
      for (int r = 0; r < 4; ++r) {
        int m = mt * 16 + quad * 4 + r;
        int l1 = t0 - 5 + m;
        unsigned short hv = f2b(fmaxf(acc[nt][r], 0.f));
        s_c1[m][co] = (l1 >= 0 && l1 < 999) ? hv : (unsigned short)0;
      }
    }
  }
  __syncthreads();

  // ---- conv2
  for (int mt = wave; mt < 5; mt += 4) {
    f32x4 acc[4];
#pragma unroll
    for (int nt = 0; nt < 4; ++nt) {
      float bv = cb2[nt * 16 + l15];
      acc[nt] = (f32x4){bv, bv, bv, bv};
    }
    for (int kt = 0; kt < 6; ++kt) {
      bf16x8 a = *(const bf16x8*)&s_c1[mt * 16 + l15 + kt][quad * 8];
#pragma unroll
      for (int nt = 0; nt < 4; ++nt) {
        bf16x8 bf = *(const bf16x8*)(wt2 + (kt * 64 + nt * 16 + l15) * 32 + quad * 8);
        acc[nt] = __builtin_amdgcn_mfma_f32_16x16x32_bf16(a, bf, acc[nt], 0, 0, 0);
      }
    }
#pragma unroll
    for (int nt = 0; nt < 4; ++nt) {
      int co = nt * 16 + l15;
#pragma unroll
      for (int r = 0; r < 4; ++r) {
        int m = mt * 16 + quad * 4 + r;
        int l2 = t0 - 3 + m;
        unsigned short hv = f2b(fmaxf(acc[nt][r], 0.f));
        s_c2[m][co] = (l2 >= 0 && l2 < 998) ? hv : (unsigned short)0;
      }
    }
  }
  __syncthreads();

  // ---- conv3 + relu-max epilogue
  {
    int mt = wave;
    f32x4 acc[6];
#pragma unroll
    for (int nt = 0; nt < 6; ++nt) {
      float bv = cb3[nt * 16 + l15];
      acc[nt] = (f32x4){bv, bv, bv, bv};
    }
    for (int kt = 0; kt < 8; ++kt) {
      int arow = mt * 16 + l15 + kt;
#pragma unroll
      for (int cb = 0; cb < 2; ++cb) {
        bf16x8 a = *(const bf16x8*)&s_c2[arow][cb * 32 + quad * 8];
#pragma unroll
        for (int nt = 0; nt < 6; ++nt) {
          bf16x8 bf = *(const bf16x8*)(wt3 + (kt * 96 + nt * 16 + l15) * 64 + cb * 32 + quad * 8);
          acc[nt] = __builtin_amdgcn_mfma_f32_16x16x32_bf16(a, bf, acc[nt], 0, 0, 0);
        }
      }
    }
#pragma unroll
    for (int nt = 0; nt < 6; ++nt) {
      float mx = 0.f;  // relu folded: max(0, .)
#pragma unroll
      for (int r = 0; r < 4; ++r) {
        int l3 = t0 + mt * 16 + quad * 4 + r;
        if (l3 < 997) mx = fmaxf(mx, acc[nt][r]);
      }
      atomicMax(&s_max[nt * 16 + l15], __float_as_int(mx));
    }
  }
  __syncthreads();
  if (tid < 96) atomicMax((int*)&outmax[b * 224 + 128 + tid], s_max[tid]);
}

// ---------------- final 256 -> 1 ----------------
__global__ void k_fc3(const float* __restrict__ in, const float* __restrict__ w,
                      const float* __restrict__ bias, float* __restrict__ out) {
  int b = blockIdx.x * 256 + threadIdx.x;
  if (b >= NB) return;
  float acc = bias[0];
#pragma unroll 4
  for (int k = 0; k < 256; ++k) acc += in[b * 256 + k] * w[k];
  out[b] = acc;
}

extern "C" void kernel_launch(void* const* d_in, const int* in_sizes, int n_in,
                              void* d_out, int out_size, void* d_ws, size_t ws_size,
                              hipStream_t stream) {
  (void)in_sizes; (void)n_in; (void)out_size; (void)ws_size;
  const float* x = (const float*)d_in[0];
  const int* ei = (const int*)d_in[1];
  const int* batch = (const int*)d_in[2];
  const int* seq = (const int*)d_in[3];
  const float* W1 = (const float*)d_in[4];
  // b1/b2/b3 (d_in[5,9,13]) dropped: constant channel bias cancels in BatchNorm
  const float* g1 = (const float*)d_in[6];
  const float* bt1 = (const float*)d_in[7];
  const float* W2 = (const float*)d_in[8];
  const float* g2 = (const float*)d_in[10];
  const float* bt2 = (const float*)d_in[11];
  const float* W3 = (const float*)d_in[12];
  const float* g3 = (const float*)d_in[14];
  const float* bt3 = (const float*)d_in[15];
  const float* emb = (const float*)d_in[16];
  const float* ck1 = (const float*)d_in[17];
  const float* cb1 = (const float*)d_in[18];
  const float* ck2 = (const float*)d_in[19];
  const float* cb2 = (const float*)d_in[20];
  const float* ck3 = (const float*)d_in[21];
  const float* cb3 = (const float*)d_in[22];
  const float* fw1 = (const float*)d_in[23];
  const float* fb1 = (const float*)d_in[24];
  const float* fw2 = (const float*)d_in[25];
  const float* fb2 = (const float*)d_in[26];
  const float* fw3 = (const float*)d_in[27];
  const float* fb3 = (const float*)d_in[28];
  const int* src = ei;
  const int* dst = ei + NE;

  float* ws = (float*)d_ws;
  float* bufA = ws;                 // 32768*128 (16 MB)
  float* bufB = ws + 4194304;       // 32768*128 (16 MB)
  float* dis = ws + 8388608;        // 32768
  float* stats = ws + 8421376;      // 256
  float* cbuf = ws + 8421632;       // 512*224  (ends 8536320)
  // bf16 area
  unsigned short* emb_bf = (unsigned short*)(ws + 8536832);  // 3328
  unsigned short* wt1 = emb_bf + 3328;                       // 16384
  unsigned short* wt2 = wt1 + 16384;                         // 12288
  unsigned short* wt3 = wt2 + 12288;                         // 49152 (ends float 8577408)
  // CSR area
  int* degi = (int*)(ws + 8577408);       // 32768
  int* base = degi + NN;                  // 32769
  int* cursor = base + NN + 1;            // 32768
  unsigned short* csr_src = (unsigned short*)(cursor + NN);  // 131072 u16 (ends ~34.9 MB)
  float* out = (float*)d_out;

  hipMemsetAsync(degi, 0, NN * sizeof(int), stream);
  hipMemsetAsync(cbuf, 0, NB * 224 * sizeof(float), stream);

  k_prep<<<318, 256, 0, stream>>>(emb, ck1, ck2, ck3, emb_bf, wt1, wt2, wt3);
  k_degi<<<NE / 256, 256, 0, stream>>>(dst, degi, NE);
  k_dis2<<<NN / 256, 256, 0, stream>>>(degi, dis, NN);
  k_scan<<<1, 1024, 0, stream>>>(degi, base, cursor);
  k_fill<<<NE / 256, 256, 0, stream>>>(src, dst, cursor, csr_src, NE);

  // ---- GCN layer 1 (5 -> 64)
  k_fc<64, 5, false, false><<<NN * 16 / 256, 256, 0, stream>>>(x, W1, nullptr, bufB, NN);
  k_gather<64><<<NN / 4, 256, 0, stream>>>(bufB, dis, base, csr_src, bufA, NN);
  hipMemsetAsync(stats, 0, 128 * sizeof(float), stream);
  k_bnstats<64><<<256, 256, 0, stream>>>(bufA, stats, NN);
  k_bnfinal<64><<<1, 64, 0, stream>>>(stats, g1, bt1, NN);
  k_bnrelu<64><<<NN * 16 / 256, 256, 0, stream>>>(bufA, stats, NN);

  // ---- GCN layer 2 (64 -> 128)
  k_fc<128, 64, false, false><<<NN * 32 / 256, 256, 0, stream>>>(bufA, W2, nullptr, bufB, NN);
  k_gather<128><<<NN / 2, 256, 0, stream>>>(bufB, dis, base, csr_src, bufA, NN);
  hipMemsetAsync(stats, 0, 256 * sizeof(float), stream);
  k_bnstats<128><<<256, 256, 0, stream>>>(bufA, stats, NN);
  k_bnfinal<128><<<1, 128, 0, stream>>>(stats, g2, bt2, NN);
  k_bnrelu<128><<<NN * 32 / 256, 256, 0, stream>>>(bufA, stats, NN);

  // ---- GCN layer 3 (128 -> 128)
  k_fc<128, 128, false, false><<<NN * 32 / 256, 256, 0, stream>>>(bufA, W3, nullptr, bufB, NN);
  k_gather<128><<<NN / 2, 256, 0, stream>>>(bufB, dis, base, csr_src, bufA, NN);
  hipMemsetAsync(stats, 0, 256 * sizeof(float), stream);
  k_bnstats<128><<<256, 256, 0, stream>>>(bufA, stats, NN);
  k_bnfinal<128><<<1, 128, 0, stream>>>(stats, g3, bt3, NN);
  k_bnrelu<128><<<NN * 32 / 256, 256, 0, stream>>>(bufA, stats, NN);

  // ---- graph mean pool -> cbuf[:, 0:128]
  k_pool2<<<NB, 128, 0, stream>>>(bufA, batch, cbuf);

  // ---- protein encoder -> cbuf[:, 128:224]
  conv_mfma<<<dim3(16, NB), 256, 0, stream>>>(seq, emb_bf, wt1, cb1, wt2, cb2, wt3, cb3, cbuf);

  // ---- regressor
  k_fc<512, 224, true, true><<<NB * 128 / 256, 256, 0, stream>>>(cbuf, fw1, fb1, bufB, NB);
  k_fc<256, 512, true, true><<<NB * 64 / 256, 256, 0, stream>>>(bufB, fw2, fb2, bufA, NB);
  k_fc3<<<2, 256, 0, stream>>>(bufA, fw3, fb3, out);
}

// Round 7
// 695.774 us; speedup vs baseline: 11.8561x; 1.6142x over previous
//
#include <hip/hip_runtime.h>

#define NN 32768
#define NE 131072
#define NB 512
#define SL 1000

using bf16x8 = __attribute__((ext_vector_type(8))) short;
using f32x4  = __attribute__((ext_vector_type(4))) float;

static __device__ __forceinline__ unsigned short f2b(float f) {
  union { float f; unsigned u; } x; x.f = f;
  unsigned r = x.u + 0x7fffu + ((x.u >> 16) & 1u);  // RNE
  return (unsigned short)(r >> 16);
}

// ---------------- degree (int) / normalization ----------------
__global__ void k_degi(const int* __restrict__ dst, int* __restrict__ degi, int E) {
  int e = blockIdx.x * 256 + threadIdx.x;
  if (e < E) atomicAdd(&degi[dst[e]], 1);
}
__global__ void k_dis2(const int* __restrict__ degi, float* __restrict__ dis, int N) {
  int i = blockIdx.x * 256 + threadIdx.x;
  if (i < N) dis[i] = rsqrtf(1.0f + (float)degi[i]);
}

// ---------------- CSR build: scan (1 block) + fill ----------------
__global__ void k_scan(const int* __restrict__ degi, int* __restrict__ base,
                       int* __restrict__ cursor) {
  __shared__ int part[1024];
  int tid = threadIdx.x;
  int v[32];
  int s = 0;
  int lo = tid * 32;
#pragma unroll
  for (int i = 0; i < 32; ++i) { v[i] = degi[lo + i]; s += v[i]; }
  part[tid] = s;
  __syncthreads();
  for (int off = 1; off < 1024; off <<= 1) {
    int val = (tid >= off) ? part[tid - off] : 0;
    __syncthreads();
    part[tid] += val;
    __syncthreads();
  }
  int run = (tid > 0) ? part[tid - 1] : 0;
#pragma unroll
  for (int i = 0; i < 32; ++i) {
    base[lo + i] = run;
    cursor[lo + i] = run;
    run += v[i];
  }
  if (tid == 1023) base[NN] = run;
}

__global__ void k_fill(const int* __restrict__ src, const int* __restrict__ dst,
                       int* __restrict__ cursor, unsigned short* __restrict__ csr_src, int E) {
  int e = blockIdx.x * 256 + threadIdx.x;
  if (e < E) {
    int d = dst[e];
    int pos = atomicAdd(&cursor[d], 1);
    csr_src[pos] = (unsigned short)src[e];  // node ids < 32768 fit in u16
  }
}

// ---------------- GCN aggregate (gather, incl. self-loop term) ----------------
template<int C>
__global__ void k_gather(const float* __restrict__ xw, const float* __restrict__ dis,
                         const int* __restrict__ base, const unsigned short* __restrict__ csr_src,
                         float* __restrict__ agg, int N) {
  constexpr int NPB = 256 / C;
  int n = blockIdx.x * NPB + threadIdx.x / C;
  if (n >= N) return;
  int c = threadIdx.x & (C - 1);
  float dn = dis[n];
  float acc = xw[(long)n * C + c] * dn * dn;
  int b0 = base[n], b1 = base[n + 1];
  for (int j = b0; j < b1; ++j) {
    int s = csr_src[j];
    acc += xw[(long)s * C + c] * (dis[s] * dn);
  }
  agg[(long)n * C + c] = acc;
}

// ---------------- weight prep: fp32 [co][ci][k] -> bf16 [k][co][ci]; emb -> bf16 ----------------
__global__ void k_prep(const float* __restrict__ emb, const float* __restrict__ ck1,
                       const float* __restrict__ ck2, const float* __restrict__ ck3,
                       unsigned short* __restrict__ emb_bf, unsigned short* __restrict__ wt1,
                       unsigned short* __restrict__ wt2, unsigned short* __restrict__ wt3) {
  int idx = blockIdx.x * 256 + threadIdx.x;
  if (idx < 3328) {                       // emb 26x128
    emb_bf[idx] = f2b(emb[idx]);
  } else if (idx < 3328 + 16384) {        // wt1[k<4][co<32][ci<128]
    int i = idx - 3328;
    int kt = i >> 12, co = (i >> 7) & 31, ci = i & 127;
    wt1[i] = f2b(ck1[co * 512 + ci * 4 + kt]);
  } else if (idx < 3328 + 16384 + 12288) { // wt2[k<6][co<64][ci<32]
    int i = idx - 3328 - 16384;
    int kt = i >> 11, co = (i >> 5) & 63, ci = i & 31;
    wt2[i] = f2b(ck2[co * 192 + ci * 6 + kt]);
  } else if (idx < 3328 + 16384 + 12288 + 49152) { // wt3[k<8][co<96][ci<64]
    int i = idx - 3328 - 16384 - 12288;
    int kt = i / 6144, co = (i >> 6) % 96, ci = i & 63;
    wt3[i] = f2b(ck3[co * 512 + ci * 8 + kt]);
  }
}

// ---------------- generic dense layer (fp32, GNN xw + regressor) ----------------
template<int C_OUT, int K, bool RELU, bool BIAS>
__launch_bounds__(256)
__global__ void k_fc(const float* __restrict__ in, const float* __restrict__ W,
                     const float* __restrict__ bias, float* __restrict__ out, int N) {
  constexpr int CO4 = C_OUT / 4;
  int gid = blockIdx.x * 256 + threadIdx.x;
  int n = gid / CO4;
  if (n >= N) return;
  int co = (gid - n * CO4) * 4;
  const float* row = in + (long)n * K;
  float ax = 0.f, ay = 0.f, az = 0.f, aw = 0.f;
  if (BIAS) {
    float4 b4 = *(const float4*)&bias[co];
    ax = b4.x; ay = b4.y; az = b4.z; aw = b4.w;
  }
#pragma unroll 4
  for (int ci = 0; ci < K; ++ci) {
    float a = row[ci];
    float4 w = *(const float4*)&W[(long)ci * C_OUT + co];
    ax += a * w.x; ay += a * w.y; az += a * w.z; aw += a * w.w;
  }
  if (RELU) {
    ax = fmaxf(ax, 0.f); ay = fmaxf(ay, 0.f); az = fmaxf(az, 0.f); aw = fmaxf(aw, 0.f);
  }
  float4 o; o.x = ax; o.y = ay; o.z = az; o.w = aw;
  *(float4*)&out[(long)n * C_OUT + co] = o;
}

// ---------------- batchnorm ----------------
template<int C>
__global__ void k_bnstats(const float* __restrict__ h, float* __restrict__ stats, int N) {
  constexpr int RPB = 256 / C;
  int c = threadIdx.x % C;
  int r = threadIdx.x / C;
  float s = 0.f, ss = 0.f;
  for (int n = blockIdx.x * RPB + r; n < N; n += gridDim.x * RPB) {
    float v = h[(long)n * C + c];
    s += v; ss += v * v;
  }
  __shared__ float ls[256], lss[256];
  ls[threadIdx.x] = s; lss[threadIdx.x] = ss;
  __syncthreads();
  if (threadIdx.x < C) {
    float st = 0.f, sst = 0.f;
#pragma unroll
    for (int r2 = 0; r2 < RPB; ++r2) { st += ls[c + r2 * C]; sst += lss[c + r2 * C]; }
    atomicAdd(&stats[c], st);
    atomicAdd(&stats[C + c], sst);
  }
}

template<int C>
__global__ void k_bnfinal(float* stats, const float* __restrict__ g,
                          const float* __restrict__ bt, int N) {
  int c = threadIdx.x;
  float m = stats[c] / (float)N;
  float v = stats[C + c] / (float)N - m * m;
  float sc = g[c] * rsqrtf(v + 1e-5f);
  stats[c] = sc;
  stats[C + c] = bt[c] - m * sc;
}

template<int C>
__global__ void k_bnrelu(float* __restrict__ h, const float* __restrict__ stats, int N) {
  constexpr int C4 = C / 4;
  int gid = blockIdx.x * 256 + threadIdx.x;
  int n = gid / C4;
  if (n >= N) return;
  int c = (gid - n * C4) * 4;
  float4 v = *(float4*)&h[(long)n * C + c];
  float4 sc = *(const float4*)&stats[c];
  float4 sh = *(const float4*)&stats[C + c];
  v.x = fmaxf(v.x * sc.x + sh.x, 0.f);
  v.y = fmaxf(v.y * sc.y + sh.y, 0.f);
  v.z = fmaxf(v.z * sc.z + sh.z, 0.f);
  v.w = fmaxf(v.w * sc.w + sh.w, 0.f);
  *(float4*)&h[(long)n * C + c] = v;
}

// ---------------- graph mean-pool (sorted batch -> binary search ranges) ----------------
__global__ void k_pool2(const float* __restrict__ h, const int* __restrict__ batch,
                        float* __restrict__ cbuf) {
  int b = blockIdx.x;
  __shared__ int s_lo, s_hi;
  if (threadIdx.x == 0) {
    int lo = 0, hi = NN;
    while (lo < hi) { int m = (lo + hi) >> 1; if (batch[m] < b) lo = m + 1; else hi = m; }
    s_lo = lo;
    hi = NN;
    while (lo < hi) { int m = (lo + hi) >> 1; if (batch[m] <= b) lo = m + 1; else hi = m; }
    s_hi = lo;
  }
  __syncthreads();
  int lo = s_lo, hi = s_hi;
  int c = threadIdx.x;  // 128 threads = 128 channels
  float s = 0.f;
  for (int n = lo; n < hi; ++n) s += h[(long)n * 128 + c];
  cbuf[b * 224 + c] = s / fmaxf((float)(hi - lo), 1.0f);
}

// ---------------- protein encoder: bf16 MFMA, 128-output tiles, LDS weights ----------------
// Block = (tile of 128 conv3 outputs, batch b), grid (8, 512). 4 waves.
// Row chains (m = storage row):  s_c1 row m <-> l1 = t0-5+m (rows 0..143, 144..151 zero)
//                                s_c2 row m <-> l2 = t0-3+m (rows 0..143)
// conv1: M=144 (9 mt), N=32, K=512;  A from emb_bf via s_tok[m+kt] (idx<147)
// conv2: M=144 (9 mt), N=64, K=192;  A = s_c1[m+kt] (rows<149)
// conv3: M=128 (8 mt), N=96, K=512;  A = s_c2[m+kt] (rows<135)
// Weights staged in LDS with +8-ushort row padding (breaks 16-way bank conflicts):
//   wt1 whole [128][136], wt2 whole [384][40], wt3 per-kt slice [96][72] double-buffered.
// Register blocking: conv1 2mt x 2nt (+wave0 mt=8), conv2 2mt x 4nt (+wave0 mt=8),
// conv3 2mt x 6nt = 12 acc chains.  Masks: l1<999 / l2<998 zero-store; l3<997 in max.
// Plain __launch_bounds__(256): a min-waves hint causes catastrophic spill (round 3).
__launch_bounds__(256)
__global__ void conv_mfma(const int* __restrict__ seq, const unsigned short* __restrict__ emb_bf,
                          const unsigned short* __restrict__ wt1g, const float* __restrict__ cb1,
                          const unsigned short* __restrict__ wt2g, const float* __restrict__ cb2,
                          const unsigned short* __restrict__ wt3g, const float* __restrict__ cb3,
                          float* __restrict__ outmax) {
  __shared__ __align__(16) unsigned short s_w[17408];     // 34816 B weight union
  __shared__ __align__(16) unsigned short s_c1[152][40];  // 12160 B
  __shared__ __align__(16) unsigned short s_c2[144][72];  // 20736 B
  __shared__ int s_tok[152];
  __shared__ int s_max[96];

  int tid = threadIdx.x;
  int t0 = blockIdx.x * 128;
  int b = blockIdx.y;

  if (tid < 96) s_max[tid] = 0;
  if (tid < 152) {
    int p = t0 - 6 + tid;
    s_tok[tid] = (p >= 0 && p < SL) ? seq[b * SL + p] : 0;  // tok 0 row all-zero
  }
  if (tid < 160) ((int*)&s_c1[144][0])[tid] = 0;  // zero guard rows 144..151

  // stage wt1 (2048 x 16B chunks) -> [row=kt*32+co][136]
  for (int c = 0; c < 8; ++c) {
    int ch = c * 256 + tid;
    int row = ch >> 4, col = (ch & 15) * 8;
    *(bf16x8*)&s_w[row * 136 + col] = *(const bf16x8*)(wt1g + ch * 8);
  }
  __syncthreads();

  int lane = tid & 63, wave = tid >> 6;
  int l15 = lane & 15, quad = lane >> 4;

  // ---- conv1: pairs (wave, wave+4) x 2 nt, then wave0 does mt=8
  {
    int mt0 = wave, mt1 = wave + 4;
    f32x4 acc[2][2];
#pragma unroll
    for (int nt = 0; nt < 2; ++nt) {
      float bv = cb1[nt * 16 + l15];
      acc[0][nt] = (f32x4){bv, bv, bv, bv};
      acc[1][nt] = (f32x4){bv, bv, bv, bv};
    }
    for (int kt = 0; kt < 4; ++kt) {
      const unsigned short* e0 = emb_bf + s_tok[mt0 * 16 + l15 + kt] * 128 + quad * 8;
      const unsigned short* e1 = emb_bf + s_tok[mt1 * 16 + l15 + kt] * 128 + quad * 8;
#pragma unroll
      for (int cb = 0; cb < 4; ++cb) {
        bf16x8 a0 = *(const bf16x8*)(e0 + cb * 32);
        bf16x8 a1 = *(const bf16x8*)(e1 + cb * 32);
#pragma unroll
        for (int nt = 0; nt < 2; ++nt) {
          bf16x8 bf = *(const bf16x8*)&s_w[(kt * 32 + nt * 16 + l15) * 136 + cb * 32 + quad * 8];
          acc[0][nt] = __builtin_amdgcn_mfma_f32_16x16x32_bf16(a0, bf, acc[0][nt], 0, 0, 0);
          acc[1][nt] = __builtin_amdgcn_mfma_f32_16x16x32_bf16(a1, bf, acc[1][nt], 0, 0, 0);
        }
      }
    }
#pragma unroll
    for (int mb = 0; mb < 2; ++mb) {
      int mt = mb ? mt1 : mt0;
#pragma unroll
      for (int nt = 0; nt < 2; ++nt) {
        int co = nt * 16 + l15;
#pragma unroll
        for (int r = 0; r < 4; ++r) {
          int m = mt * 16 + quad * 4 + r;
          int l1 = t0 - 5 + m;
          unsigned short hv = f2b(fmaxf(acc[mb][nt][r], 0.f));
          s_c1[m][co] = (l1 >= 0 && l1 < 999) ? hv : (unsigned short)0;
        }
      }
    }
    if (wave == 0) {  // mt = 8
      f32x4 acc8[2];
#pragma unroll
      for (int nt = 0; nt < 2; ++nt) {
        float bv = cb1[nt * 16 + l15];
        acc8[nt] = (f32x4){bv, bv, bv, bv};
      }
      for (int kt = 0; kt < 4; ++kt) {
        const unsigned short* e0 = emb_bf + s_tok[128 + l15 + kt] * 128 + quad * 8;
#pragma unroll
        for (int cb = 0; cb < 4; ++cb) {
          bf16x8 a0 = *(const bf16x8*)(e0 + cb * 32);
#pragma unroll
          for (int nt = 0; nt < 2; ++nt) {
            bf16x8 bf = *(const bf16x8*)&s_w[(kt * 32 + nt * 16 + l15) * 136 + cb * 32 + quad * 8];
            acc8[nt] = __builtin_amdgcn_mfma_f32_16x16x32_bf16(a0, bf, acc8[nt], 0, 0, 0);
          }
        }
      }
#pragma unroll
      for (int nt = 0; nt < 2; ++nt) {
        int co = nt * 16 + l15;
#pragma unroll
        for (int r = 0; r < 4; ++r) {
          int m = 128 + quad * 4 + r;
          int l1 = t0 - 5 + m;
          unsigned short hv = f2b(fmaxf(acc8[nt][r], 0.f));
          s_c1[m][co] = (l1 >= 0 && l1 < 999) ? hv : (unsigned short)0;
        }
      }
    }
  }

  // stage wt2 (1536 chunks) -> [row=kt*64+co][40]; loads issued pre-barrier
  {
    bf16x8 w2t[6];
#pragma unroll
    for (int c = 0; c < 6; ++c) w2t[c] = *(const bf16x8*)(wt2g + (c * 256 + tid) * 8);
    __syncthreads();  // conv1 done reading wt1 + s_c1 writes visible
#pragma unroll
    for (int c = 0; c < 6; ++c) {
      int ch = c * 256 + tid;
      int row = ch >> 2, col = (ch & 3) * 8;
      *(bf16x8*)&s_w[row * 40 + col] = w2t[c];
    }
    __syncthreads();
  }

  // ---- conv2: pairs (wave, wave+4) x 4 nt, then wave0 does mt=8
  {
    int mt0 = wave, mt1 = wave + 4;
    f32x4 acc[2][4];
#pragma unroll
    for (int nt = 0; nt < 4; ++nt) {
      float bv = cb2[nt * 16 + l15];
      acc[0][nt] = (f32x4){bv, bv, bv, bv};
      acc[1][nt] = (f32x4){bv, bv, bv, bv};
    }
    for (int kt = 0; kt < 6; ++kt) {
      bf16x8 a0 = *(const bf16x8*)&s_c1[mt0 * 16 + l15 + kt][quad * 8];
      bf16x8 a1 = *(const bf16x8*)&s_c1[mt1 * 16 + l15 + kt][quad * 8];
#pragma unroll
      for (int nt = 0; nt < 4; ++nt) {
        bf16x8 bf = *(const bf16x8*)&s_w[(kt * 64 + nt * 16 + l15) * 40 + quad * 8];
        acc[0][nt] = __builtin_amdgcn_mfma_f32_16x16x32_bf16(a0, bf, acc[0][nt], 0, 0, 0);
        acc[1][nt] = __builtin_amdgcn_mfma_f32_16x16x32_bf16(a1, bf, acc[1][nt], 0, 0, 0);
      }
    }
#pragma unroll
    for (int mb = 0; mb < 2; ++mb) {
      int mt = mb ? mt1 : mt0;
#pragma unroll
      for (int nt = 0; nt < 4; ++nt) {
        int co = nt * 16 + l15;
#pragma unroll
        for (int r = 0; r < 4; ++r) {
          int m = mt * 16 + quad * 4 + r;
          int l2 = t0 - 3 + m;
          unsigned short hv = f2b(fmaxf(acc[mb][nt][r], 0.f));
          s_c2[m][co] = (l2 >= 0 && l2 < 998) ? hv : (unsigned short)0;
        }
      }
    }
    if (wave == 0) {  // mt = 8
      f32x4 acc8[4];
#pragma unroll
      for (int nt = 0; nt < 4; ++nt) {
        float bv = cb2[nt * 16 + l15];
        acc8[nt] = (f32x4){bv, bv, bv, bv};
      }
      for (int kt = 0; kt < 6; ++kt) {
        bf16x8 a0 = *(const bf16x8*)&s_c1[128 + l15 + kt][quad * 8];
#pragma unroll
        for (int nt = 0; nt < 4; ++nt) {
          bf16x8 bf = *(const bf16x8*)&s_w[(kt * 64 + nt * 16 + l15) * 40 + quad * 8];
          acc8[nt] = __builtin_amdgcn_mfma_f32_16x16x32_bf16(a0, bf, acc8[nt], 0, 0, 0);
        }
      }
#pragma unroll
      for (int nt = 0; nt < 4; ++nt) {
        int co = nt * 16 + l15;
#pragma unroll
        for (int r = 0; r < 4; ++r) {
          int m = 128 + quad * 4 + r;
          int l2 = t0 - 3 + m;
          unsigned short hv = f2b(fmaxf(acc8[nt][r], 0.f));
          s_c2[m][co] = (l2 >= 0 && l2 < 998) ? hv : (unsigned short)0;
        }
      }
    }
  }

  // stage wt3 slice 0 -> buf0 [96][72]
  {
    bf16x8 w3t[3];
#pragma unroll
    for (int c = 0; c < 3; ++c) w3t[c] = *(const bf16x8*)(wt3g + (c * 256 + tid) * 8);
    __syncthreads();  // conv2 done reading wt2 + s_c2 writes visible
#pragma unroll
    for (int c = 0; c < 3; ++c) {
      int ch = c * 256 + tid;
      int row = ch >> 3, col = (ch & 7) * 8;
      *(bf16x8*)&s_w[row * 72 + col] = w3t[c];
    }
    __syncthreads();
  }

  // ---- conv3: 2 mt x 6 nt, wt3 kt-slices double-buffered
  {
    int mt0 = wave, mt1 = wave + 4;
    f32x4 acc[2][6];
#pragma unroll
    for (int nt = 0; nt < 6; ++nt) {
      float bv = cb3[nt * 16 + l15];
      acc[0][nt] = (f32x4){bv, bv, bv, bv};
      acc[1][nt] = (f32x4){bv, bv, bv, bv};
    }
    for (int kt = 0; kt < 8; ++kt) {
      bf16x8 w3t[3];
      if (kt < 7) {
#pragma unroll
        for (int c = 0; c < 3; ++c)
          w3t[c] = *(const bf16x8*)(wt3g + ((kt + 1) * 768 + c * 256 + tid) * 8);
      }
      int bo = (kt & 1) * 6912;
#pragma unroll
      for (int cb = 0; cb < 2; ++cb) {
        bf16x8 a0 = *(const bf16x8*)&s_c2[mt0 * 16 + l15 + kt][cb * 32 + quad * 8];
        bf16x8 a1 = *(const bf16x8*)&s_c2[mt1 * 16 + l15 + kt][cb * 32 + quad * 8];
#pragma unroll
        for (int nt = 0; nt < 6; ++nt) {
          bf16x8 bf = *(const bf16x8*)&s_w[bo + (nt * 16 + l15) * 72 + cb * 32 + quad * 8];
          acc[0][nt] = __builtin_amdgcn_mfma_f32_16x16x32_bf16(a0, bf, acc[0][nt], 0, 0, 0);
          acc[1][nt] = __builtin_amdgcn_mfma_f32_16x16x32_bf16(a1, bf, acc[1][nt], 0, 0, 0);
        }
      }
      if (kt < 7) {
        int bo2 = ((kt + 1) & 1) * 6912;
#pragma unroll
        for (int c = 0; c < 3; ++c) {
          int ch = c * 256 + tid;
          int row = ch >> 3, col = (ch & 7) * 8;
          *(bf16x8*)&s_w[bo2 + row * 72 + col] = w3t[c];
        }
      }
      __syncthreads();
    }
#pragma unroll
    for (int nt = 0; nt < 6; ++nt) {
      int co = nt * 16 + l15;
      float mx = 0.f;  // relu folded
#pragma unroll
      for (int mb = 0; mb < 2; ++mb) {
        int mt = mb ? mt1 : mt0;
#pragma unroll
        for (int r = 0; r < 4; ++r) {
          int l3 = t0 + mt * 16 + quad * 4 + r;
          if (l3 < 997) mx = fmaxf(mx, acc[mb][nt][r]);
        }
      }
      atomicMax(&s_max[co], __float_as_int(mx));
    }
  }
  __syncthreads();
  if (tid < 96) atomicMax((int*)&outmax[b * 224 + 128 + tid], s_max[tid]);
}

// ---------------- final 256 -> 1 ----------------
__global__ void k_fc3(const float* __restrict__ in, const float* __restrict__ w,
                      const float* __restrict__ bias, float* __restrict__ out) {
  int b = blockIdx.x * 256 + threadIdx.x;
  if (b >= NB) return;
  float acc = bias[0];
#pragma unroll 4
  for (int k = 0; k < 256; ++k) acc += in[b * 256 + k] * w[k];
  out[b] = acc;
}

extern "C" void kernel_launch(void* const* d_in, const int* in_sizes, int n_in,
                              void* d_out, int out_size, void* d_ws, size_t ws_size,
                              hipStream_t stream) {
  (void)in_sizes; (void)n_in; (void)out_size; (void)ws_size;
  const float* x = (const float*)d_in[0];
  const int* ei = (const int*)d_in[1];
  const int* batch = (const int*)d_in[2];
  const int* seq = (const int*)d_in[3];
  const float* W1 = (const float*)d_in[4];
  // b1/b2/b3 (d_in[5,9,13]) dropped: constant channel bias cancels in BatchNorm
  const float* g1 = (const float*)d_in[6];
  const float* bt1 = (const float*)d_in[7];
  const float* W2 = (const float*)d_in[8];
  const float* g2 = (const float*)d_in[10];
  const float* bt2 = (const float*)d_in[11];
  const float* W3 = (const float*)d_in[12];
  const float* g3 = (const float*)d_in[14];
  const float* bt3 = (const float*)d_in[15];
  const float* emb = (const float*)d_in[16];
  const float* ck1 = (const float*)d_in[17];
  const float* cb1 = (const float*)d_in[18];
  const float* ck2 = (const float*)d_in[19];
  const float* cb2 = (const float*)d_in[20];
  const float* ck3 = (const float*)d_in[21];
  const float* cb3 = (const float*)d_in[22];
  const float* fw1 = (const float*)d_in[23];
  const float* fb1 = (const float*)d_in[24];
  const float* fw2 = (const float*)d_in[25];
  const float* fb2 = (const float*)d_in[26];
  const float* fw3 = (const float*)d_in[27];
  const float* fb3 = (const float*)d_in[28];
  const int* src = ei;
  const int* dst = ei + NE;

  float* ws = (float*)d_ws;
  float* bufA = ws;                 // 32768*128 (16 MB)
  float* bufB = ws + 4194304;       // 32768*128 (16 MB)
  float* dis = ws + 8388608;        // 32768
  float* stats = ws + 8421376;      // 256
  float* cbuf = ws + 8421632;       // 512*224  (ends 8536320)
  // bf16 area
  unsigned short* emb_bf = (unsigned short*)(ws + 8536832);  // 3328
  unsigned short* wt1 = emb_bf + 3328;                       // 16384
  unsigned short* wt2 = wt1 + 16384;                         // 12288
  unsigned short* wt3 = wt2 + 12288;                         // 49152 (ends float 8577408)
  // CSR area
  int* degi = (int*)(ws + 8577408);       // 32768
  int* base = degi + NN;                  // 32769
  int* cursor = base + NN + 1;            // 32768
  unsigned short* csr_src = (unsigned short*)(cursor + NN);  // 131072 u16
  float* out = (float*)d_out;

  hipMemsetAsync(degi, 0, NN * sizeof(int), stream);
  hipMemsetAsync(cbuf, 0, NB * 224 * sizeof(float), stream);

  k_prep<<<318, 256, 0, stream>>>(emb, ck1, ck2, ck3, emb_bf, wt1, wt2, wt3);
  k_degi<<<NE / 256, 256, 0, stream>>>(dst, degi, NE);
  k_dis2<<<NN / 256, 256, 0, stream>>>(degi, dis, NN);
  k_scan<<<1, 1024, 0, stream>>>(degi, base, cursor);
  k_fill<<<NE / 256, 256, 0, stream>>>(src, dst, cursor, csr_src, NE);

  // ---- GCN layer 1 (5 -> 64)
  k_fc<64, 5, false, false><<<NN * 16 / 256, 256, 0, stream>>>(x, W1, nullptr, bufB, NN);
  k_gather<64><<<NN / 4, 256, 0, stream>>>(bufB, dis, base, csr_src, bufA, NN);
  hipMemsetAsync(stats, 0, 128 * sizeof(float), stream);
  k_bnstats<64><<<256, 256, 0, stream>>>(bufA, stats, NN);
  k_bnfinal<64><<<1, 64, 0, stream>>>(stats, g1, bt1, NN);
  k_bnrelu<64><<<NN * 16 / 256, 256, 0, stream>>>(bufA, stats, NN);

  // ---- GCN layer 2 (64 -> 128)
  k_fc<128, 64, false, false><<<NN * 32 / 256, 256, 0, stream>>>(bufA, W2, nullptr, bufB, NN);
  k_gather<128><<<NN / 2, 256, 0, stream>>>(bufB, dis, base, csr_src, bufA, NN);
  hipMemsetAsync(stats, 0, 256 * sizeof(float), stream);
  k_bnstats<128><<<256, 256, 0, stream>>>(bufA, stats, NN);
  k_bnfinal<128><<<1, 128, 0, stream>>>(stats, g2, bt2, NN);
  k_bnrelu<128><<<NN * 32 / 256, 256, 0, stream>>>(bufA, stats, NN);

  // ---- GCN layer 3 (128 -> 128)
  k_fc<128, 128, false, false><<<NN * 32 / 256, 256, 0, stream>>>(bufA, W3, nullptr, bufB, NN);
  k_gather<128><<<NN / 2, 256, 0, stream>>>(bufB, dis, base, csr_src, bufA, NN);
  hipMemsetAsync(stats, 0, 256 * sizeof(float), stream);
  k_bnstats<128><<<256, 256, 0, stream>>>(bufA, stats, NN);
  k_bnfinal<128><<<1, 128, 0, stream>>>(stats, g3, bt3, NN);
  k_bnrelu<128><<<NN * 32 / 256, 256, 0, stream>>>(bufA, stats, NN);

  // ---- graph mean pool -> cbuf[:, 0:128]
  k_pool2<<<NB, 128, 0, stream>>>(bufA, batch, cbuf);

  // ---- protein encoder -> cbuf[:, 128:224]
  conv_mfma<<<dim3(8, NB), 256, 0, stream>>>(seq, emb_bf, wt1, cb1, wt2, cb2, wt3, cb3, cbuf);

  // ---- regressor
  k_fc<512, 224, true, true><<<NB * 128 / 256, 256, 0, stream>>>(cbuf, fw1, fb1, bufB, NB);
  k_fc<256, 512, true, true><<<NB * 64 / 256, 256, 0, stream>>>(bufB, fw2, fb2, bufA, NB);
  k_fc3<<<2, 256, 0, stream>>>(bufA, fw3, fb3, out);
}

// Round 8
// 610.369 us; speedup vs baseline: 13.5151x; 1.1399x over previous
//
#include <hip/hip_runtime.h>

#define NN 32768
#define NE 131072
#define NB 512
#define SL 1000

using bf16x8 = __attribute__((ext_vector_type(8))) short;
using f32x4  = __attribute__((ext_vector_type(4))) float;

static __device__ __forceinline__ unsigned short f2b(float f) {
  union { float f; unsigned u; } x; x.f = f;
  unsigned r = x.u + 0x7fffu + ((x.u >> 16) & 1u);  // RNE
  return (unsigned short)(r >> 16);
}

// ---------------- degree (int) / normalization ----------------
__global__ void k_degi(const int* __restrict__ dst, int* __restrict__ degi, int E) {
  int e = blockIdx.x * 256 + threadIdx.x;
  if (e < E) atomicAdd(&degi[dst[e]], 1);
}
__global__ void k_dis2(const int* __restrict__ degi, float* __restrict__ dis, int N) {
  int i = blockIdx.x * 256 + threadIdx.x;
  if (i < N) dis[i] = rsqrtf(1.0f + (float)degi[i]);
}

// ---------------- CSR build: scan (1 block) + fill ----------------
__global__ void k_scan(const int* __restrict__ degi, int* __restrict__ base,
                       int* __restrict__ cursor) {
  __shared__ int part[1024];
  int tid = threadIdx.x;
  int v[32];
  int s = 0;
  int lo = tid * 32;
#pragma unroll
  for (int i = 0; i < 32; ++i) { v[i] = degi[lo + i]; s += v[i]; }
  part[tid] = s;
  __syncthreads();
  for (int off = 1; off < 1024; off <<= 1) {
    int val = (tid >= off) ? part[tid - off] : 0;
    __syncthreads();
    part[tid] += val;
    __syncthreads();
  }
  int run = (tid > 0) ? part[tid - 1] : 0;
#pragma unroll
  for (int i = 0; i < 32; ++i) {
    base[lo + i] = run;
    cursor[lo + i] = run;
    run += v[i];
  }
  if (tid == 1023) base[NN] = run;
}

__global__ void k_fill(const int* __restrict__ src, const int* __restrict__ dst,
                       int* __restrict__ cursor, unsigned short* __restrict__ csr_src, int E) {
  int e = blockIdx.x * 256 + threadIdx.x;
  if (e < E) {
    int d = dst[e];
    int pos = atomicAdd(&cursor[d], 1);
    csr_src[pos] = (unsigned short)src[e];  // node ids < 32768 fit in u16
  }
}

// ---------------- GCN aggregate (gather, incl. self-loop term), float4/thread ----------------
template<int C>
__global__ void k_gather4(const float* __restrict__ xw, const float* __restrict__ dis,
                          const int* __restrict__ base, const unsigned short* __restrict__ csr_src,
                          float* __restrict__ agg, int N) {
  constexpr int TPN = C / 4;
  int t = blockIdx.x * 256 + threadIdx.x;
  int n = t / TPN;
  if (n >= N) return;
  int c = (t % TPN) * 4;
  float dn = dis[n];
  float s2 = dn * dn;
  float4 acc = *(const float4*)&xw[(long)n * C + c];
  acc.x *= s2; acc.y *= s2; acc.z *= s2; acc.w *= s2;
  int b0 = base[n], b1 = base[n + 1];
  for (int j = b0; j < b1; ++j) {
    int s = csr_src[j];
    float coef = dis[s] * dn;
    float4 v = *(const float4*)&xw[(long)s * C + c];
    acc.x += v.x * coef; acc.y += v.y * coef;
    acc.z += v.z * coef; acc.w += v.w * coef;
  }
  *(float4*)&agg[(long)n * C + c] = acc;
}

// ---------------- weight prep: fp32 [co][ci][k] -> bf16 [k][co][ci]; emb -> bf16 ----------------
__global__ void k_prep(const float* __restrict__ emb, const float* __restrict__ ck1,
                       const float* __restrict__ ck2, const float* __restrict__ ck3,
                       unsigned short* __restrict__ emb_bf, unsigned short* __restrict__ wt1,
                       unsigned short* __restrict__ wt2, unsigned short* __restrict__ wt3) {
  int idx = blockIdx.x * 256 + threadIdx.x;
  if (idx < 3328) {                       // emb 26x128
    emb_bf[idx] = f2b(emb[idx]);
  } else if (idx < 3328 + 16384) {        // wt1[k<4][co<32][ci<128]
    int i = idx - 3328;
    int kt = i >> 12, co = (i >> 7) & 31, ci = i & 127;
    wt1[i] = f2b(ck1[co * 512 + ci * 4 + kt]);
  } else if (idx < 3328 + 16384 + 12288) { // wt2[k<6][co<64][ci<32]
    int i = idx - 3328 - 16384;
    int kt = i >> 11, co = (i >> 5) & 63, ci = i & 31;
    wt2[i] = f2b(ck2[co * 192 + ci * 6 + kt]);
  } else if (idx < 3328 + 16384 + 12288 + 49152) { // wt3[k<8][co<96][ci<64]
    int i = idx - 3328 - 16384 - 12288;
    int kt = i / 6144, co = (i >> 6) % 96, ci = i & 63;
    wt3[i] = f2b(ck3[co * 512 + ci * 8 + kt]);
  }
}

// ---------------- simple dense layer (layer 1, K=5) ----------------
template<int C_OUT, int K, bool RELU, bool BIAS>
__launch_bounds__(256)
__global__ void k_fc(const float* __restrict__ in, const float* __restrict__ W,
                     const float* __restrict__ bias, float* __restrict__ out, int N) {
  constexpr int CO4 = C_OUT / 4;
  int gid = blockIdx.x * 256 + threadIdx.x;
  int n = gid / CO4;
  if (n >= N) return;
  int co = (gid - n * CO4) * 4;
  const float* row = in + (long)n * K;
  float ax = 0.f, ay = 0.f, az = 0.f, aw = 0.f;
  if (BIAS) {
    float4 b4 = *(const float4*)&bias[co];
    ax = b4.x; ay = b4.y; az = b4.z; aw = b4.w;
  }
#pragma unroll 4
  for (int ci = 0; ci < K; ++ci) {
    float a = row[ci];
    float4 w = *(const float4*)&W[(long)ci * C_OUT + co];
    ax += a * w.x; ay += a * w.y; az += a * w.z; aw += a * w.w;
  }
  if (RELU) {
    ax = fmaxf(ax, 0.f); ay = fmaxf(ay, 0.f); az = fmaxf(az, 0.f); aw = fmaxf(aw, 0.f);
  }
  float4 o; o.x = ax; o.y = ay; o.z = az; o.w = aw;
  *(float4*)&out[(long)n * C_OUT + co] = o;
}

// ---------------- register-tiled dense layer: TN nodes x 4 co per thread ----------------
// Bitwise-identical accumulation order to k_fc (ci ascending per output).
template<int C_OUT, int K, int TN, bool RELU, bool BIAS>
__launch_bounds__(256)
__global__ void k_fc4(const float* __restrict__ in, const float* __restrict__ W,
                      const float* __restrict__ bias, float* __restrict__ out, int N) {
  constexpr int CO4 = C_OUT / 4;
  constexpr int GPB = 256 / CO4;
  int g = blockIdx.x * GPB + threadIdx.x / CO4;
  long n0 = (long)g * TN;
  if (n0 >= N) return;
  int co = (threadIdx.x % CO4) * 4;
  float4 acc[TN];
  float4 b4 = {0.f, 0.f, 0.f, 0.f};
  if (BIAS) b4 = *(const float4*)&bias[co];
#pragma unroll
  for (int t = 0; t < TN; ++t) acc[t] = b4;
  for (int ci = 0; ci < K; ci += 4) {
    float4 w0 = *(const float4*)&W[(long)(ci + 0) * C_OUT + co];
    float4 w1 = *(const float4*)&W[(long)(ci + 1) * C_OUT + co];
    float4 w2 = *(const float4*)&W[(long)(ci + 2) * C_OUT + co];
    float4 w3 = *(const float4*)&W[(long)(ci + 3) * C_OUT + co];
#pragma unroll
    for (int t = 0; t < TN; ++t) {
      float4 a = *(const float4*)&in[(n0 + t) * K + ci];
      acc[t].x += a.x * w0.x; acc[t].y += a.x * w0.y; acc[t].z += a.x * w0.z; acc[t].w += a.x * w0.w;
      acc[t].x += a.y * w1.x; acc[t].y += a.y * w1.y; acc[t].z += a.y * w1.z; acc[t].w += a.y * w1.w;
      acc[t].x += a.z * w2.x; acc[t].y += a.z * w2.y; acc[t].z += a.z * w2.z; acc[t].w += a.z * w2.w;
      acc[t].x += a.w * w3.x; acc[t].y += a.w * w3.y; acc[t].z += a.w * w3.z; acc[t].w += a.w * w3.w;
    }
  }
#pragma unroll
  for (int t = 0; t < TN; ++t) {
    float4 o = acc[t];
    if (RELU) {
      o.x = fmaxf(o.x, 0.f); o.y = fmaxf(o.y, 0.f);
      o.z = fmaxf(o.z, 0.f); o.w = fmaxf(o.w, 0.f);
    }
    *(float4*)&out[(n0 + t) * C_OUT + co] = o;
  }
}

// ---------------- batchnorm ----------------
template<int C>
__global__ void k_bnstats(const float* __restrict__ h, float* __restrict__ stats, int N) {
  constexpr int RPB = 256 / C;
  int c = threadIdx.x % C;
  int r = threadIdx.x / C;
  float s = 0.f, ss = 0.f;
  for (int n = blockIdx.x * RPB + r; n < N; n += gridDim.x * RPB) {
    float v = h[(long)n * C + c];
    s += v; ss += v * v;
  }
  __shared__ float ls[256], lss[256];
  ls[threadIdx.x] = s; lss[threadIdx.x] = ss;
  __syncthreads();
  if (threadIdx.x < C) {
    float st = 0.f, sst = 0.f;
#pragma unroll
    for (int r2 = 0; r2 < RPB; ++r2) { st += ls[c + r2 * C]; sst += lss[c + r2 * C]; }
    atomicAdd(&stats[c], st);
    atomicAdd(&stats[C + c], sst);
  }
}

template<int C>
__global__ void k_bnfinal(float* stats, const float* __restrict__ g,
                          const float* __restrict__ bt, int N) {
  int c = threadIdx.x;
  float m = stats[c] / (float)N;
  float v = stats[C + c] / (float)N - m * m;
  float sc = g[c] * rsqrtf(v + 1e-5f);
  stats[c] = sc;
  stats[C + c] = bt[c] - m * sc;
}

template<int C>
__global__ void k_bnrelu(float* __restrict__ h, const float* __restrict__ stats, int N) {
  constexpr int C4 = C / 4;
  int gid = blockIdx.x * 256 + threadIdx.x;
  int n = gid / C4;
  if (n >= N) return;
  int c = (gid - n * C4) * 4;
  float4 v = *(float4*)&h[(long)n * C + c];
  float4 sc = *(const float4*)&stats[c];
  float4 sh = *(const float4*)&stats[C + c];
  v.x = fmaxf(v.x * sc.x + sh.x, 0.f);
  v.y = fmaxf(v.y * sc.y + sh.y, 0.f);
  v.z = fmaxf(v.z * sc.z + sh.z, 0.f);
  v.w = fmaxf(v.w * sc.w + sh.w, 0.f);
  *(float4*)&h[(long)n * C + c] = v;
}

// ---------------- fused BN+relu+mean-pool over sorted batch ranges ----------------
// Reads layer-3 agg directly (no materialized h).  Same n-order as bnrelu+pool.
__global__ void k_pool2bn(const float* __restrict__ agg, const float* __restrict__ stats,
                          const int* __restrict__ batch, float* __restrict__ cbuf) {
  int b = blockIdx.x;
  __shared__ int s_lo, s_hi;
  if (threadIdx.x == 0) {
    int lo = 0, hi = NN;
    while (lo < hi) { int m = (lo + hi) >> 1; if (batch[m] < b) lo = m + 1; else hi = m; }
    s_lo = lo;
    hi = NN;
    while (lo < hi) { int m = (lo + hi) >> 1; if (batch[m] <= b) lo = m + 1; else hi = m; }
    s_hi = lo;
  }
  __syncthreads();
  int lo = s_lo, hi = s_hi;
  int c = threadIdx.x;  // 128 threads = 128 channels
  float sc = stats[c], sh = stats[128 + c];
  float s = 0.f;
  for (int n = lo; n < hi; ++n) s += fmaxf(agg[(long)n * 128 + c] * sc + sh, 0.f);
  cbuf[b * 224 + c] = s / fmaxf((float)(hi - lo), 1.0f);
}

// ---------------- protein encoder: bf16 MFMA, 128-output tiles, LDS weights ----------------
// (unchanged from round 7 — 162 us, MfmaUtil 22%)
__launch_bounds__(256)
__global__ void conv_mfma(const int* __restrict__ seq, const unsigned short* __restrict__ emb_bf,
                          const unsigned short* __restrict__ wt1g, const float* __restrict__ cb1,
                          const unsigned short* __restrict__ wt2g, const float* __restrict__ cb2,
                          const unsigned short* __restrict__ wt3g, const float* __restrict__ cb3,
                          float* __restrict__ outmax) {
  __shared__ __align__(16) unsigned short s_w[17408];     // 34816 B weight union
  __shared__ __align__(16) unsigned short s_c1[152][40];  // 12160 B
  __shared__ __align__(16) unsigned short s_c2[144][72];  // 20736 B
  __shared__ int s_tok[152];
  __shared__ int s_max[96];

  int tid = threadIdx.x;
  int t0 = blockIdx.x * 128;
  int b = blockIdx.y;

  if (tid < 96) s_max[tid] = 0;
  if (tid < 152) {
    int p = t0 - 6 + tid;
    s_tok[tid] = (p >= 0 && p < SL) ? seq[b * SL + p] : 0;  // tok 0 row all-zero
  }
  if (tid < 160) ((int*)&s_c1[144][0])[tid] = 0;  // zero guard rows 144..151

  // stage wt1 (2048 x 16B chunks) -> [row=kt*32+co][136]
  for (int c = 0; c < 8; ++c) {
    int ch = c * 256 + tid;
    int row = ch >> 4, col = (ch & 15) * 8;
    *(bf16x8*)&s_w[row * 136 + col] = *(const bf16x8*)(wt1g + ch * 8);
  }
  __syncthreads();

  int lane = tid & 63, wave = tid >> 6;
  int l15 = lane & 15, quad = lane >> 4;

  // ---- conv1: pairs (wave, wave+4) x 2 nt, then wave0 does mt=8
  {
    int mt0 = wave, mt1 = wave + 4;
    f32x4 acc[2][2];
#pragma unroll
    for (int nt = 0; nt < 2; ++nt) {
      float bv = cb1[nt * 16 + l15];
      acc[0][nt] = (f32x4){bv, bv, bv, bv};
      acc[1][nt] = (f32x4){bv, bv, bv, bv};
    }
    for (int kt = 0; kt < 4; ++kt) {
      const unsigned short* e0 = emb_bf + s_tok[mt0 * 16 + l15 + kt] * 128 + quad * 8;
      const unsigned short* e1 = emb_bf + s_tok[mt1 * 16 + l15 + kt] * 128 + quad * 8;
#pragma unroll
      for (int cb = 0; cb < 4; ++cb) {
        bf16x8 a0 = *(const bf16x8*)(e0 + cb * 32);
        bf16x8 a1 = *(const bf16x8*)(e1 + cb * 32);
#pragma unroll
        for (int nt = 0; nt < 2; ++nt) {
          bf16x8 bf = *(const bf16x8*)&s_w[(kt * 32 + nt * 16 + l15) * 136 + cb * 32 + quad * 8];
          acc[0][nt] = __builtin_amdgcn_mfma_f32_16x16x32_bf16(a0, bf, acc[0][nt], 0, 0, 0);
          acc[1][nt] = __builtin_amdgcn_mfma_f32_16x16x32_bf16(a1, bf, acc[1][nt], 0, 0, 0);
        }
      }
    }
#pragma unroll
    for (int mb = 0; mb < 2; ++mb) {
      int mt = mb ? mt1 : mt0;
#pragma unroll
      for (int nt = 0; nt < 2; ++nt) {
        int co = nt * 16 + l15;
#pragma unroll
        for (int r = 0; r < 4; ++r) {
          int m = mt * 16 + quad * 4 + r;
          int l1 = t0 - 5 + m;
          unsigned short hv = f2b(fmaxf(acc[mb][nt][r], 0.f));
          s_c1[m][co] = (l1 >= 0 && l1 < 999) ? hv : (unsigned short)0;
        }
      }
    }
    if (wave == 0) {  // mt = 8
      f32x4 acc8[2];
#pragma unroll
      for (int nt = 0; nt < 2; ++nt) {
        float bv = cb1[nt * 16 + l15];
        acc8[nt] = (f32x4){bv, bv, bv, bv};
      }
      for (int kt = 0; kt < 4; ++kt) {
        const unsigned short* e0 = emb_bf + s_tok[128 + l15 + kt] * 128 + quad * 8;
#pragma unroll
        for (int cb = 0; cb < 4; ++cb) {
          bf16x8 a0 = *(const bf16x8*)(e0 + cb * 32);
#pragma unroll
          for (int nt = 0; nt < 2; ++nt) {
            bf16x8 bf = *(const bf16x8*)&s_w[(kt * 32 + nt * 16 + l15) * 136 + cb * 32 + quad * 8];
            acc8[nt] = __builtin_amdgcn_mfma_f32_16x16x32_bf16(a0, bf, acc8[nt], 0, 0, 0);
          }
        }
      }
#pragma unroll
      for (int nt = 0; nt < 2; ++nt) {
        int co = nt * 16 + l15;
#pragma unroll
        for (int r = 0; r < 4; ++r) {
          int m = 128 + quad * 4 + r;
          int l1 = t0 - 5 + m;
          unsigned short hv = f2b(fmaxf(acc8[nt][r], 0.f));
          s_c1[m][co] = (l1 >= 0 && l1 < 999) ? hv : (unsigned short)0;
        }
      }
    }
  }

  // stage wt2 (1536 chunks) -> [row=kt*64+co][40]; loads issued pre-barrier
  {
    bf16x8 w2t[6];
#pragma unroll
    for (int c = 0; c < 6; ++c) w2t[c] = *(const bf16x8*)(wt2g + (c * 256 + tid) * 8);
    __syncthreads();  // conv1 done reading wt1 + s_c1 writes visible
#pragma unroll
    for (int c = 0; c < 6; ++c) {
      int ch = c * 256 + tid;
      int row = ch >> 2, col = (ch & 3) * 8;
      *(bf16x8*)&s_w[row * 40 + col] = w2t[c];
    }
    __syncthreads();
  }

  // ---- conv2: pairs (wave, wave+4) x 4 nt, then wave0 does mt=8
  {
    int mt0 = wave, mt1 = wave + 4;
    f32x4 acc[2][4];
#pragma unroll
    for (int nt = 0; nt < 4; ++nt) {
      float bv = cb2[nt * 16 + l15];
      acc[0][nt] = (f32x4){bv, bv, bv, bv};
      acc[1][nt] = (f32x4){bv, bv, bv, bv};
    }
    for (int kt = 0; kt < 6; ++kt) {
      bf16x8 a0 = *(const bf16x8*)&s_c1[mt0 * 16 + l15 + kt][quad * 8];
      bf16x8 a1 = *(const bf16x8*)&s_c1[mt1 * 16 + l15 + kt][quad * 8];
#pragma unroll
      for (int nt = 0; nt < 4; ++nt) {
        bf16x8 bf = *(const bf16x8*)&s_w[(kt * 64 + nt * 16 + l15) * 40 + quad * 8];
        acc[0][nt] = __builtin_amdgcn_mfma_f32_16x16x32_bf16(a0, bf, acc[0][nt], 0, 0, 0);
        acc[1][nt] = __builtin_amdgcn_mfma_f32_16x16x32_bf16(a1, bf, acc[1][nt], 0, 0, 0);
      }
    }
#pragma unroll
    for (int mb = 0; mb < 2; ++mb) {
      int mt = mb ? mt1 : mt0;
#pragma unroll
      for (int nt = 0; nt < 4; ++nt) {
        int co = nt * 16 + l15;
#pragma unroll
        for (int r = 0; r < 4; ++r) {
          int m = mt * 16 + quad * 4 + r;
          int l2 = t0 - 3 + m;
          unsigned short hv = f2b(fmaxf(acc[mb][nt][r], 0.f));
          s_c2[m][co] = (l2 >= 0 && l2 < 998) ? hv : (unsigned short)0;
        }
      }
    }
    if (wave == 0) {  // mt = 8
      f32x4 acc8[4];
#pragma unroll
      for (int nt = 0; nt < 4; ++nt) {
        float bv = cb2[nt * 16 + l15];
        acc8[nt] = (f32x4){bv, bv, bv, bv};
      }
      for (int kt = 0; kt < 6; ++kt) {
        bf16x8 a0 = *(const bf16x8*)&s_c1[128 + l15 + kt][quad * 8];
#pragma unroll
        for (int nt = 0; nt < 4; ++nt) {
          bf16x8 bf = *(const bf16x8*)&s_w[(kt * 64 + nt * 16 + l15) * 40 + quad * 8];
          acc8[nt] = __builtin_amdgcn_mfma_f32_16x16x32_bf16(a0, bf, acc8[nt], 0, 0, 0);
        }
      }
#pragma unroll
      for (int nt = 0; nt < 4; ++nt) {
        int co = nt * 16 + l15;
#pragma unroll
        for (int r = 0; r < 4; ++r) {
          int m = 128 + quad * 4 + r;
          int l2 = t0 - 3 + m;
          unsigned short hv = f2b(fmaxf(acc8[nt][r], 0.f));
          s_c2[m][co] = (l2 >= 0 && l2 < 998) ? hv : (unsigned short)0;
        }
      }
    }
  }

  // stage wt3 slice 0 -> buf0 [96][72]
  {
    bf16x8 w3t[3];
#pragma unroll
    for (int c = 0; c < 3; ++c) w3t[c] = *(const bf16x8*)(wt3g + (c * 256 + tid) * 8);
    __syncthreads();  // conv2 done reading wt2 + s_c2 writes visible
#pragma unroll
    for (int c = 0; c < 3; ++c) {
      int ch = c * 256 + tid;
      int row = ch >> 3, col = (ch & 7) * 8;
      *(bf16x8*)&s_w[row * 72 + col] = w3t[c];
    }
    __syncthreads();
  }

  // ---- conv3: 2 mt x 6 nt, wt3 kt-slices double-buffered
  {
    int mt0 = wave, mt1 = wave + 4;
    f32x4 acc[2][6];
#pragma unroll
    for (int nt = 0; nt < 6; ++nt) {
      float bv = cb3[nt * 16 + l15];
      acc[0][nt] = (f32x4){bv, bv, bv, bv};
      acc[1][nt] = (f32x4){bv, bv, bv, bv};
    }
    for (int kt = 0; kt < 8; ++kt) {
      bf16x8 w3t[3];
      if (kt < 7) {
#pragma unroll
        for (int c = 0; c < 3; ++c)
          w3t[c] = *(const bf16x8*)(wt3g + ((kt + 1) * 768 + c * 256 + tid) * 8);
      }
      int bo = (kt & 1) * 6912;
#pragma unroll
      for (int cb = 0; cb < 2; ++cb) {
        bf16x8 a0 = *(const bf16x8*)&s_c2[mt0 * 16 + l15 + kt][cb * 32 + quad * 8];
        bf16x8 a1 = *(const bf16x8*)&s_c2[mt1 * 16 + l15 + kt][cb * 32 + quad * 8];
#pragma unroll
        for (int nt = 0; nt < 6; ++nt) {
          bf16x8 bf = *(const bf16x8*)&s_w[bo + (nt * 16 + l15) * 72 + cb * 32 + quad * 8];
          acc[0][nt] = __builtin_amdgcn_mfma_f32_16x16x32_bf16(a0, bf, acc[0][nt], 0, 0, 0);
          acc[1][nt] = __builtin_amdgcn_mfma_f32_16x16x32_bf16(a1, bf, acc[1][nt], 0, 0, 0);
        }
      }
      if (kt < 7) {
        int bo2 = ((kt + 1) & 1) * 6912;
#pragma unroll
        for (int c = 0; c < 3; ++c) {
          int ch = c * 256 + tid;
          int row = ch >> 3, col = (ch & 7) * 8;
          *(bf16x8*)&s_w[bo2 + row * 72 + col] = w3t[c];
        }
      }
      __syncthreads();
    }
#pragma unroll
    for (int nt = 0; nt < 6; ++nt) {
      int co = nt * 16 + l15;
      float mx = 0.f;  // relu folded
#pragma unroll
      for (int mb = 0; mb < 2; ++mb) {
        int mt = mb ? mt1 : mt0;
#pragma unroll
        for (int r = 0; r < 4; ++r) {
          int l3 = t0 + mt * 16 + quad * 4 + r;
          if (l3 < 997) mx = fmaxf(mx, acc[mb][nt][r]);
        }
      }
      atomicMax(&s_max[co], __float_as_int(mx));
    }
  }
  __syncthreads();
  if (tid < 96) atomicMax((int*)&outmax[b * 224 + 128 + tid], s_max[tid]);
}

// ---------------- final 256 -> 1 ----------------
__global__ void k_fc3(const float* __restrict__ in, const float* __restrict__ w,
                      const float* __restrict__ bias, float* __restrict__ out) {
  int b = blockIdx.x * 256 + threadIdx.x;
  if (b >= NB) return;
  float acc = bias[0];
#pragma unroll 4
  for (int k = 0; k < 256; ++k) acc += in[b * 256 + k] * w[k];
  out[b] = acc;
}

extern "C" void kernel_launch(void* const* d_in, const int* in_sizes, int n_in,
                              void* d_out, int out_size, void* d_ws, size_t ws_size,
                              hipStream_t stream) {
  (void)in_sizes; (void)n_in; (void)out_size; (void)ws_size;
  const float* x = (const float*)d_in[0];
  const int* ei = (const int*)d_in[1];
  const int* batch = (const int*)d_in[2];
  const int* seq = (const int*)d_in[3];
  const float* W1 = (const float*)d_in[4];
  // b1/b2/b3 (d_in[5,9,13]) dropped: constant channel bias cancels in BatchNorm
  const float* g1 = (const float*)d_in[6];
  const float* bt1 = (const float*)d_in[7];
  const float* W2 = (const float*)d_in[8];
  const float* g2 = (const float*)d_in[10];
  const float* bt2 = (const float*)d_in[11];
  const float* W3 = (const float*)d_in[12];
  const float* g3 = (const float*)d_in[14];
  const float* bt3 = (const float*)d_in[15];
  const float* emb = (const float*)d_in[16];
  const float* ck1 = (const float*)d_in[17];
  const float* cb1 = (const float*)d_in[18];
  const float* ck2 = (const float*)d_in[19];
  const float* cb2 = (const float*)d_in[20];
  const float* ck3 = (const float*)d_in[21];
  const float* cb3 = (const float*)d_in[22];
  const float* fw1 = (const float*)d_in[23];
  const float* fb1 = (const float*)d_in[24];
  const float* fw2 = (const float*)d_in[25];
  const float* fb2 = (const float*)d_in[26];
  const float* fw3 = (const float*)d_in[27];
  const float* fb3 = (const float*)d_in[28];
  const int* src = ei;
  const int* dst = ei + NE;

  float* ws = (float*)d_ws;
  float* bufA = ws;                 // 32768*128 (16 MB)
  float* bufB = ws + 4194304;       // 32768*128 (16 MB)
  float* dis = ws + 8388608;        // 32768
  float* stats = ws + 8421376;      // 640 floats: L1@0(128), L2@128(256), L3@384(256)
  float* cbuf = ws + 8422016;       // 512*224
  // bf16 area
  unsigned short* emb_bf = (unsigned short*)(ws + 8536832);  // 3328
  unsigned short* wt1 = emb_bf + 3328;                       // 16384
  unsigned short* wt2 = wt1 + 16384;                         // 12288
  unsigned short* wt3 = wt2 + 12288;                         // 49152
  // CSR area
  int* degi = (int*)(ws + 8577408);       // 32768
  int* base = degi + NN;                  // 32769
  int* cursor = base + NN + 1;            // 32768
  unsigned short* csr_src = (unsigned short*)(cursor + NN);  // 131072 u16
  float* out = (float*)d_out;

  hipMemsetAsync(degi, 0, NN * sizeof(int), stream);
  hipMemsetAsync(stats, 0, 640 * sizeof(float), stream);
  hipMemsetAsync(cbuf, 0, NB * 224 * sizeof(float), stream);

  k_prep<<<318, 256, 0, stream>>>(emb, ck1, ck2, ck3, emb_bf, wt1, wt2, wt3);
  k_degi<<<NE / 256, 256, 0, stream>>>(dst, degi, NE);
  k_dis2<<<NN / 256, 256, 0, stream>>>(degi, dis, NN);
  k_scan<<<1, 1024, 0, stream>>>(degi, base, cursor);
  k_fill<<<NE / 256, 256, 0, stream>>>(src, dst, cursor, csr_src, NE);

  // ---- GCN layer 1 (5 -> 64)
  k_fc<64, 5, false, false><<<NN * 16 / 256, 256, 0, stream>>>(x, W1, nullptr, bufB, NN);
  k_gather4<64><<<NN * 16 / 256, 256, 0, stream>>>(bufB, dis, base, csr_src, bufA, NN);
  k_bnstats<64><<<256, 256, 0, stream>>>(bufA, stats, NN);
  k_bnfinal<64><<<1, 64, 0, stream>>>(stats, g1, bt1, NN);
  k_bnrelu<64><<<NN * 16 / 256, 256, 0, stream>>>(bufA, stats, NN);

  // ---- GCN layer 2 (64 -> 128)
  k_fc4<128, 64, 4, false, false><<<1024, 256, 0, stream>>>(bufA, W2, nullptr, bufB, NN);
  k_gather4<128><<<NN * 32 / 256, 256, 0, stream>>>(bufB, dis, base, csr_src, bufA, NN);
  k_bnstats<128><<<256, 256, 0, stream>>>(bufA, stats + 128, NN);
  k_bnfinal<128><<<1, 128, 0, stream>>>(stats + 128, g2, bt2, NN);
  k_bnrelu<128><<<NN * 32 / 256, 256, 0, stream>>>(bufA, stats + 128, NN);

  // ---- GCN layer 3 (128 -> 128); h never materialized (bn+relu fused into pool)
  k_fc4<128, 128, 4, false, false><<<1024, 256, 0, stream>>>(bufA, W3, nullptr, bufB, NN);
  k_gather4<128><<<NN * 32 / 256, 256, 0, stream>>>(bufB, dis, base, csr_src, bufA, NN);
  k_bnstats<128><<<256, 256, 0, stream>>>(bufA, stats + 384, NN);
  k_bnfinal<128><<<1, 128, 0, stream>>>(stats + 384, g3, bt3, NN);

  // ---- fused BN+relu+mean pool -> cbuf[:, 0:128]
  k_pool2bn<<<NB, 128, 0, stream>>>(bufA, stats + 384, batch, cbuf);

  // ---- protein encoder -> cbuf[:, 128:224]
  conv_mfma<<<dim3(8, NB), 256, 0, stream>>>(seq, emb_bf, wt1, cb1, wt2, cb2, wt3, cb3, cbuf);

  // ---- regressor
  k_fc4<512, 224, 4, true, true><<<64, 256, 0, stream>>>(cbuf, fw1, fb1, bufB, NB);
  k_fc4<256, 512, 4, true, true><<<32, 256, 0, stream>>>(bufB, fw2, fb2, bufA, NB);
  k_fc3<<<2, 256, 0, stream>>>(bufA, fw3, fb3, out);
}